// Round 1
// baseline (351.955 us; speedup 1.0000x reference)
//
#include <hip/hip_runtime.h>
#include <cstdint>
#include <cstddef>

// GraphAttentionLayer: N=8192, IN=512, OUT=256
// Pipeline:
//  k0: w1=W@W2[:256], w2=W@W2[256:], WTb = bf16(W^T)
//  k1: Wh1 = X@w1, Wh2 = X@w2 (exact fp32), global max(Wh2) via atomicMax key
//  k2: WhT = bf16(X@W)^T  [256][8192]  (bf16 MFMA GEMM)
//  k3: fused mask+lrelu+softmax-weights + (attention @ Wh) partial over K-split
//  k4: reduce partials, divide by Z, relu
#define NR 8192
#define FOUT 256
#define KIN 512
#define KSPLIT 4
#define JCHUNK (NR / KSPLIT)  // 2048
#define BKJ 64                // j per step in k3
#define NSTEP (JCHUNK / BKJ)  // 32

typedef __attribute__((ext_vector_type(8))) short bf16x8;
typedef __attribute__((ext_vector_type(4))) float f32x4;

__device__ __forceinline__ unsigned f2bf(float x) {
  unsigned u = __float_as_uint(x);
  u += 0x7fffu + ((u >> 16) & 1u);
  return u >> 16;
}
__device__ __forceinline__ float bf2f(unsigned h) {
  return __uint_as_float(h << 16);
}
// monotone float->uint key for atomicMax (memset-0 == -inf sentinel)
__device__ __forceinline__ unsigned fkey(float x) {
  unsigned u = __float_as_uint(x);
  return (u & 0x80000000u) ? ~u : (u | 0x80000000u);
}
__device__ __forceinline__ float fkey_dec(unsigned k) {
  return __uint_as_float((k & 0x80000000u) ? (k ^ 0x80000000u) : ~k);
}

// ---------------- k0: w1, w2, WTb ----------------
__global__ __launch_bounds__(256) void k0_prep(const float* __restrict__ W,
                                               const float* __restrict__ W2,
                                               float* __restrict__ w1,
                                               float* __restrict__ w2,
                                               unsigned short* __restrict__ WTb) {
  int wv = threadIdx.x >> 6, lane = threadIdx.x & 63;
  int k = blockIdx.x * 4 + wv;  // 0..511
  int f4 = lane * 4;
  float4 wr = *(const float4*)(W + (size_t)k * FOUT + f4);
  float4 a = *(const float4*)(W2 + f4);
  float4 b = *(const float4*)(W2 + FOUT + f4);
  float d1 = wr.x * a.x + wr.y * a.y + wr.z * a.z + wr.w * a.w;
  float d2 = wr.x * b.x + wr.y * b.y + wr.z * b.z + wr.w * b.w;
#pragma unroll
  for (int off = 32; off; off >>= 1) {
    d1 += __shfl_xor(d1, off);
    d2 += __shfl_xor(d2, off);
  }
  if (lane == 0) {
    w1[k] = d1;
    w2[k] = d2;
  }
  WTb[(size_t)(f4 + 0) * KIN + k] = (unsigned short)f2bf(wr.x);
  WTb[(size_t)(f4 + 1) * KIN + k] = (unsigned short)f2bf(wr.y);
  WTb[(size_t)(f4 + 2) * KIN + k] = (unsigned short)f2bf(wr.z);
  WTb[(size_t)(f4 + 3) * KIN + k] = (unsigned short)f2bf(wr.w);
}

// ---------------- k1: Wh1, Wh2, max(Wh2) ----------------
__global__ __launch_bounds__(256) void k1_wh12(const float* __restrict__ X,
                                               const float* __restrict__ w1,
                                               const float* __restrict__ w2,
                                               float* __restrict__ Wh1,
                                               float* __restrict__ Wh2,
                                               unsigned* __restrict__ maxkey) {
  int wv = threadIdx.x >> 6, lane = threadIdx.x & 63;
  int i = blockIdx.x * 4 + wv;  // 0..8191
  const float* xp = X + (size_t)i * KIN + lane * 8;
  float4 x0 = *(const float4*)(xp);
  float4 x1 = *(const float4*)(xp + 4);
  float4 a0 = *(const float4*)(w1 + lane * 8);
  float4 a1 = *(const float4*)(w1 + lane * 8 + 4);
  float4 b0 = *(const float4*)(w2 + lane * 8);
  float4 b1 = *(const float4*)(w2 + lane * 8 + 4);
  float d1 = x0.x * a0.x + x0.y * a0.y + x0.z * a0.z + x0.w * a0.w +
             x1.x * a1.x + x1.y * a1.y + x1.z * a1.z + x1.w * a1.w;
  float d2 = x0.x * b0.x + x0.y * b0.y + x0.z * b0.z + x0.w * b0.w +
             x1.x * b1.x + x1.y * b1.y + x1.z * b1.z + x1.w * b1.w;
#pragma unroll
  for (int off = 32; off; off >>= 1) {
    d1 += __shfl_xor(d1, off);
    d2 += __shfl_xor(d2, off);
  }
  if (lane == 0) {
    Wh1[i] = d1;
    Wh2[i] = d2;
    atomicMax(maxkey, fkey(d2));
  }
}

// ---------------- k2: WhT = bf16(X@W)^T ----------------
// Block: 64 rows j, full 256 f, K=512 in 16 steps of 32.
__global__ __launch_bounds__(256) void k2_wht(const float* __restrict__ X,
                                              const unsigned short* __restrict__ WTb,
                                              unsigned short* __restrict__ WhT) {
  __shared__ char smem[4096 + 16384];  // A units 4x1KB, B units 16x1KB
  int t = threadIdx.x, wv = t >> 6, lane = t & 63;
  int jb = blockIdx.x * 64;
  int ar = t >> 2;           // row j-in-tile 0..63
  int ac = t & 3;            // k8 group
  int lB = ((t >> 2) & 15) | ((t & 3) << 4);  // shared cell index
  float4 xa, xb;
  uint4 wsr[4];
  f32x4 acc[4][4];
#pragma unroll
  for (int a = 0; a < 4; ++a)
#pragma unroll
    for (int b = 0; b < 4; ++b) acc[a][b] = (f32x4){0.f, 0.f, 0.f, 0.f};

#define K2_LOADS(KC)                                                          \
  do {                                                                        \
    const float* xp = X + (size_t)(jb + ar) * KIN + (KC) + ac * 8;            \
    xa = *(const float4*)xp;                                                  \
    xb = *(const float4*)(xp + 4);                                            \
    wsr[0] = *(const uint4*)(WTb + (size_t)((t >> 2) + 0) * KIN + (KC) + ac * 8);   \
    wsr[1] = *(const uint4*)(WTb + (size_t)((t >> 2) + 64) * KIN + (KC) + ac * 8);  \
    wsr[2] = *(const uint4*)(WTb + (size_t)((t >> 2) + 128) * KIN + (KC) + ac * 8); \
    wsr[3] = *(const uint4*)(WTb + (size_t)((t >> 2) + 192) * KIN + (KC) + ac * 8); \
  } while (0)

  K2_LOADS(0);
  for (int s = 0; s < 16; ++s) {
    uint4 ap;
    ap.x = f2bf(xa.x) | (f2bf(xa.y) << 16);
    ap.y = f2bf(xa.z) | (f2bf(xa.w) << 16);
    ap.z = f2bf(xb.x) | (f2bf(xb.y) << 16);
    ap.w = f2bf(xb.z) | (f2bf(xb.w) << 16);
    __syncthreads();
    *(uint4*)(smem + wv * 1024 + lB * 16) = ap;
#pragma unroll
    for (int p = 0; p < 4; ++p)
      *(uint4*)(smem + 4096 + (wv + p * 4) * 1024 + lB * 16) = wsr[p];
    if (s + 1 < 16) K2_LOADS((s + 1) * 32);
    __syncthreads();
    bf16x8 af[4], bfr[4];
#pragma unroll
    for (int mi = 0; mi < 4; ++mi)
      af[mi] = *(const bf16x8*)(smem + mi * 1024 + lane * 16);
#pragma unroll
    for (int nn = 0; nn < 4; ++nn)
      bfr[nn] = *(const bf16x8*)(smem + 4096 + (wv * 4 + nn) * 1024 + lane * 16);
#pragma unroll
    for (int mi = 0; mi < 4; ++mi)
#pragma unroll
      for (int nn = 0; nn < 4; ++nn)
        acc[mi][nn] = __builtin_amdgcn_mfma_f32_16x16x32_bf16(af[mi], bfr[nn],
                                                              acc[mi][nn], 0, 0, 0);
  }
#pragma unroll
  for (int mi = 0; mi < 4; ++mi)
#pragma unroll
    for (int nn = 0; nn < 4; ++nn) {
      int f = wv * 64 + nn * 16 + (lane & 15);
      int j0 = jb + mi * 16 + ((lane >> 4) << 2);
      ushort4 s4;
      s4.x = (unsigned short)f2bf(acc[mi][nn].x);
      s4.y = (unsigned short)f2bf(acc[mi][nn].y);
      s4.z = (unsigned short)f2bf(acc[mi][nn].z);
      s4.w = (unsigned short)f2bf(acc[mi][nn].w);
      *(ushort4*)(WhT + (size_t)f * NR + j0) = s4;
    }
#undef K2_LOADS
}

// ---------------- k3: fused attention-weight gen + PV matmul (partial K) ----
__device__ __forceinline__ unsigned procw(int a, float wh2v, float wh1, float m,
                                          float enm, float& z) {
  float s = wh1 + wh2v;
  float el = s > 0.f ? s : 0.2f * s;
  float w = __expf(el - m);
  w = (a > 0) ? w : enm;
  unsigned h = f2bf(w);
  z += bf2f(h);  // Z from the same bf16-rounded weights the MFMA consumes
  return h;
}

__global__ __launch_bounds__(256, 2) void k3_attn(
    const int* __restrict__ adj, const unsigned short* __restrict__ WhT,
    const float* __restrict__ Wh1, const float* __restrict__ Wh2,
    const unsigned* __restrict__ maxkey, float* __restrict__ PVp,
    float* __restrict__ Zp) {
  __shared__ char smem[8192 + 32768];  // A units 8x1KB | B units 32x1KB
  int t = threadIdx.x, wv = t >> 6, lane = t & 63;
  int kc = blockIdx.x & 3;
  int ib = blockIdx.x >> 2;  // 0..127
  int ibase = ib * 64;
  int jbch = kc * JCHUNK;
  int r0 = t >> 2;          // row in tile 0..63
  int jg = (t & 3) * 16;    // j group base 0/16/32/48
  int iglob = ibase + r0;
  float maxwh2 = fkey_dec(*maxkey);
  float wh1 = Wh1[iglob];
  float m = fmaxf(0.f, wh1 + maxwh2);
  float enm = __expf(-m);
  // A-write address (fragment-linear): unit=(r0>>4)*2+(jg>>5), cell=(r0&15)|(g<<4)
  char* awp = smem + (((r0 >> 4) * 2 + (jg >> 5)) * 1024) +
              (((r0 & 15) | (((jg & 31) >> 3) << 4)) * 16);
  int lB = ((t >> 2) & 15) | ((t & 3) << 4);
  char* bwp = smem + 8192 + wv * 2048 + lB * 16;  // + p*8192 + i2*1024
  int4 adjr[4];
  float4 wh2r[4];
  uint4 bsr[8];
  f32x4 acc[4][4];
#pragma unroll
  for (int a = 0; a < 4; ++a)
#pragma unroll
    for (int b = 0; b < 4; ++b) acc[a][b] = (f32x4){0.f, 0.f, 0.f, 0.f};
  float zacc = 0.f;

#define K3_LOADS(JC)                                                           \
  do {                                                                         \
    const int* ap = adj + ((size_t)iglob << 13) + (JC) + jg;                   \
    adjr[0] = *(const int4*)(ap);                                              \
    adjr[1] = *(const int4*)(ap + 4);                                          \
    adjr[2] = *(const int4*)(ap + 8);                                          \
    adjr[3] = *(const int4*)(ap + 12);                                         \
    const float* wp = Wh2 + (JC) + jg;                                         \
    wh2r[0] = *(const float4*)(wp);                                            \
    wh2r[1] = *(const float4*)(wp + 4);                                        \
    wh2r[2] = *(const float4*)(wp + 8);                                        \
    wh2r[3] = *(const float4*)(wp + 12);                                       \
    int fB = t >> 2;                                                           \
    int cB = (t & 3) * 8;                                                      \
    bsr[0] = *(const uint4*)(WhT + (size_t)(fB + 0) * NR + (JC) + cB);         \
    bsr[1] = *(const uint4*)(WhT + (size_t)(fB + 0) * NR + (JC) + cB + 32);    \
    bsr[2] = *(const uint4*)(WhT + (size_t)(fB + 64) * NR + (JC) + cB);        \
    bsr[3] = *(const uint4*)(WhT + (size_t)(fB + 64) * NR + (JC) + cB + 32);   \
    bsr[4] = *(const uint4*)(WhT + (size_t)(fB + 128) * NR + (JC) + cB);       \
    bsr[5] = *(const uint4*)(WhT + (size_t)(fB + 128) * NR + (JC) + cB + 32);  \
    bsr[6] = *(const uint4*)(WhT + (size_t)(fB + 192) * NR + (JC) + cB);       \
    bsr[7] = *(const uint4*)(WhT + (size_t)(fB + 192) * NR + (JC) + cB + 32);  \
  } while (0)

  K3_LOADS(jbch);
  for (int s = 0; s < NSTEP; ++s) {
    unsigned hv[16];
#pragma unroll
    for (int q = 0; q < 4; ++q) {
      int4 aq = adjr[q];
      float4 wq = wh2r[q];
      hv[q * 4 + 0] = procw(aq.x, wq.x, wh1, m, enm, zacc);
      hv[q * 4 + 1] = procw(aq.y, wq.y, wh1, m, enm, zacc);
      hv[q * 4 + 2] = procw(aq.z, wq.z, wh1, m, enm, zacc);
      hv[q * 4 + 3] = procw(aq.w, wq.w, wh1, m, enm, zacc);
    }
    uint4 A0, A1;
    A0.x = hv[0] | (hv[1] << 16);
    A0.y = hv[2] | (hv[3] << 16);
    A0.z = hv[4] | (hv[5] << 16);
    A0.w = hv[6] | (hv[7] << 16);
    A1.x = hv[8] | (hv[9] << 16);
    A1.y = hv[10] | (hv[11] << 16);
    A1.z = hv[12] | (hv[13] << 16);
    A1.w = hv[14] | (hv[15] << 16);
    __syncthreads();  // prior step's readers done with LDS
    *(uint4*)(awp) = A0;
    *(uint4*)(awp + 256) = A1;
#pragma unroll
    for (int p = 0; p < 4; ++p) {
      *(uint4*)(bwp + p * 8192 + 0) = bsr[p * 2 + 0];
      *(uint4*)(bwp + p * 8192 + 1024) = bsr[p * 2 + 1];
    }
    if (s + 1 < NSTEP) K3_LOADS(jbch + (s + 1) * BKJ);
    __syncthreads();  // LDS tiles visible
    bf16x8 af[4][2], bfr[4][2];
#pragma unroll
    for (int mi = 0; mi < 4; ++mi)
#pragma unroll
      for (int ks = 0; ks < 2; ++ks)
        af[mi][ks] = *(const bf16x8*)(smem + (mi * 2 + ks) * 1024 + lane * 16);
#pragma unroll
    for (int nn = 0; nn < 4; ++nn)
#pragma unroll
      for (int ks = 0; ks < 2; ++ks)
        bfr[nn][ks] = *(const bf16x8*)(smem + 8192 +
                                       ((wv * 4 + nn) * 2 + ks) * 1024 + lane * 16);
#pragma unroll
    for (int mi = 0; mi < 4; ++mi)
#pragma unroll
      for (int nn = 0; nn < 4; ++nn)
#pragma unroll
        for (int ks = 0; ks < 2; ++ks)
          acc[mi][nn] = __builtin_amdgcn_mfma_f32_16x16x32_bf16(
              af[mi][ks], bfr[nn][ks], acc[mi][nn], 0, 0, 0);
  }
  // Z partial: sum the 4 threads sharing a row (adjacent lanes)
  zacc += __shfl_xor(zacc, 1);
  zacc += __shfl_xor(zacc, 2);
  if ((t & 3) == 0) Zp[(size_t)kc * NR + iglob] = zacc;
#pragma unroll
  for (int mi = 0; mi < 4; ++mi)
#pragma unroll
    for (int nn = 0; nn < 4; ++nn) {
      int f = wv * 64 + nn * 16 + (lane & 15);
      int row0 = ibase + mi * 16 + ((lane >> 4) << 2);
      size_t base = ((size_t)kc * NR + row0) * FOUT + f;
      PVp[base + 0 * FOUT] = acc[mi][nn].x;
      PVp[base + 1 * FOUT] = acc[mi][nn].y;
      PVp[base + 2 * FOUT] = acc[mi][nn].z;
      PVp[base + 3 * FOUT] = acc[mi][nn].w;
    }
#undef K3_LOADS
}

// ---------------- k4: reduce partials, normalize, relu ----------------
__global__ __launch_bounds__(256) void k4_reduce(const float* __restrict__ PVp,
                                                 const float* __restrict__ Zp,
                                                 float* __restrict__ out) {
  int tid = blockIdx.x * 256 + threadIdx.x;  // 0..524287
  int i = tid >> 6;
  int f4 = (tid & 63) * 4;
  float z = Zp[i] + Zp[NR + i] + Zp[2 * NR + i] + Zp[3 * NR + i];
  float4 a = {0.f, 0.f, 0.f, 0.f};
#pragma unroll
  for (int c = 0; c < KSPLIT; ++c) {
    float4 p = *(const float4*)(PVp + ((size_t)c * NR + i) * FOUT + f4);
    a.x += p.x;
    a.y += p.y;
    a.z += p.z;
    a.w += p.w;
  }
  float inv = 1.f / z;
  float4 r;
  r.x = fmaxf(a.x * inv, 0.f);
  r.y = fmaxf(a.y * inv, 0.f);
  r.z = fmaxf(a.z * inv, 0.f);
  r.w = fmaxf(a.w * inv, 0.f);
  *(float4*)(out + (size_t)i * FOUT + f4) = r;
}

// ---------------- launch ----------------
extern "C" void kernel_launch(void* const* d_in, const int* in_sizes, int n_in,
                              void* d_out, int out_size, void* d_ws,
                              size_t ws_size, hipStream_t stream) {
  const float* X = (const float*)d_in[0];
  const float* W = (const float*)d_in[1];
  const float* W2 = (const float*)d_in[2];
  const int* adj = (const int*)d_in[3];
  float* out = (float*)d_out;
  char* ws = (char*)d_ws;

  const size_t WHT_OFF = 0;                              // ushort[256*8192]
  const size_t WTB_OFF = (size_t)4 * 1024 * 1024;        // ushort[256*512]
  const size_t W1_OFF = WTB_OFF + 256 * 1024;
  const size_t W2V_OFF = W1_OFF + 2048;
  const size_t WH1_OFF = W2V_OFF + 2048;
  const size_t WH2_OFF = WH1_OFF + 32768;
  const size_t MXK_OFF = WH2_OFF + 32768;
  const size_t ZP_OFF = MXK_OFF + 256;                   // float[4][8192]
  const size_t PV_OFF = ZP_OFF + (size_t)KSPLIT * NR * 4;  // float[4][8192][256]

  unsigned short* WhT = (unsigned short*)(ws + WHT_OFF);
  unsigned short* WTb = (unsigned short*)(ws + WTB_OFF);
  float* w1 = (float*)(ws + W1_OFF);
  float* w2 = (float*)(ws + W2V_OFF);
  float* Wh1 = (float*)(ws + WH1_OFF);
  float* Wh2 = (float*)(ws + WH2_OFF);
  unsigned* maxkey = (unsigned*)(ws + MXK_OFF);
  float* Zp = (float*)(ws + ZP_OFF);
  float* PVp = (float*)(ws + PV_OFF);

  hipMemsetAsync(maxkey, 0, 4, stream);
  k0_prep<<<128, 256, 0, stream>>>(W, W2, w1, w2, WTb);
  k1_wh12<<<2048, 256, 0, stream>>>(X, w1, w2, Wh1, Wh2, maxkey);
  k2_wht<<<128, 256, 0, stream>>>(X, WTb, WhT);
  k3_attn<<<512, 256, 0, stream>>>(adj, WhT, Wh1, Wh2, maxkey, PVp, Zp);
  k4_reduce<<<2048, 256, 0, stream>>>(PVp, Zp, out);
}

// Round 2
// 251.627 us; speedup vs baseline: 1.3987x; 1.3987x over previous
//
#include <hip/hip_runtime.h>
#include <cstdint>
#include <cstddef>

// GraphAttentionLayer: N=8192, IN=512, OUT=256
//  k0: w1=W@W2[:256], w2=W@W2[256:], WTb = bf16(W^T)
//  k1: Wh1 = X@w1, Wh2 = X@w2 (exact fp32), global max(Wh2) via atomicMax key
//  k2: WhTf = bf16(X@W)^T in MFMA-B-fragment image layout [jt][16 units][64 cells][16B]
//  k3: fused mask+lrelu+softmax-weights + (attention @ Wh), dbuf + raw-barrier +
//      counted vmcnt + global_load_lds B staging. 32-row tiles x KSPLIT=4 -> 1024 blocks.
//  k4: reduce partials, divide by Z, relu
#define NR 8192
#define FOUT 256
#define KIN 512
#define KSPLIT 4
#define JCHUNK (NR / KSPLIT)  // 2048
#define BKJ 32                // j per step in k3
#define NSTEP (JCHUNK / BKJ)  // 64
#define IROWS 32              // i-rows per k3 block

typedef __attribute__((ext_vector_type(8))) short bf16x8;
typedef __attribute__((ext_vector_type(4))) float f32x4;

__device__ __forceinline__ unsigned f2bf(float x) {
  unsigned u = __float_as_uint(x);
  u += 0x7fffu + ((u >> 16) & 1u);
  return u >> 16;
}
__device__ __forceinline__ float bf2f(unsigned h) {
  return __uint_as_float(h << 16);
}
__device__ __forceinline__ unsigned fkey(float x) {
  unsigned u = __float_as_uint(x);
  return (u & 0x80000000u) ? ~u : (u | 0x80000000u);
}
__device__ __forceinline__ float fkey_dec(unsigned k) {
  return __uint_as_float((k & 0x80000000u) ? (k ^ 0x80000000u) : ~k);
}

#define GLDS(g, l)                                                            \
  __builtin_amdgcn_global_load_lds(                                           \
      (const __attribute__((address_space(1))) unsigned int*)(g),             \
      (__attribute__((address_space(3))) unsigned int*)(l), 16, 0, 0)

// ---------------- k0: w1, w2, WTb ----------------
__global__ __launch_bounds__(256) void k0_prep(const float* __restrict__ W,
                                               const float* __restrict__ W2,
                                               float* __restrict__ w1,
                                               float* __restrict__ w2,
                                               unsigned short* __restrict__ WTb) {
  int wv = threadIdx.x >> 6, lane = threadIdx.x & 63;
  int k = blockIdx.x * 4 + wv;  // 0..511
  int f4 = lane * 4;
  float4 wr = *(const float4*)(W + (size_t)k * FOUT + f4);
  float4 a = *(const float4*)(W2 + f4);
  float4 b = *(const float4*)(W2 + FOUT + f4);
  float d1 = wr.x * a.x + wr.y * a.y + wr.z * a.z + wr.w * a.w;
  float d2 = wr.x * b.x + wr.y * b.y + wr.z * b.z + wr.w * b.w;
#pragma unroll
  for (int off = 32; off; off >>= 1) {
    d1 += __shfl_xor(d1, off);
    d2 += __shfl_xor(d2, off);
  }
  if (lane == 0) {
    w1[k] = d1;
    w2[k] = d2;
  }
  WTb[(size_t)(f4 + 0) * KIN + k] = (unsigned short)f2bf(wr.x);
  WTb[(size_t)(f4 + 1) * KIN + k] = (unsigned short)f2bf(wr.y);
  WTb[(size_t)(f4 + 2) * KIN + k] = (unsigned short)f2bf(wr.z);
  WTb[(size_t)(f4 + 3) * KIN + k] = (unsigned short)f2bf(wr.w);
}

// ---------------- k1: Wh1, Wh2, max(Wh2) ----------------
__global__ __launch_bounds__(256) void k1_wh12(const float* __restrict__ X,
                                               const float* __restrict__ w1,
                                               const float* __restrict__ w2,
                                               float* __restrict__ Wh1,
                                               float* __restrict__ Wh2,
                                               unsigned* __restrict__ maxkey) {
  int wv = threadIdx.x >> 6, lane = threadIdx.x & 63;
  int i = blockIdx.x * 4 + wv;  // 0..8191
  const float* xp = X + (size_t)i * KIN + lane * 8;
  float4 x0 = *(const float4*)(xp);
  float4 x1 = *(const float4*)(xp + 4);
  float4 a0 = *(const float4*)(w1 + lane * 8);
  float4 a1 = *(const float4*)(w1 + lane * 8 + 4);
  float4 b0 = *(const float4*)(w2 + lane * 8);
  float4 b1 = *(const float4*)(w2 + lane * 8 + 4);
  float d1 = x0.x * a0.x + x0.y * a0.y + x0.z * a0.z + x0.w * a0.w +
             x1.x * a1.x + x1.y * a1.y + x1.z * a1.z + x1.w * a1.w;
  float d2 = x0.x * b0.x + x0.y * b0.y + x0.z * b0.z + x0.w * b0.w +
             x1.x * b1.x + x1.y * b1.y + x1.z * b1.z + x1.w * b1.w;
#pragma unroll
  for (int off = 32; off; off >>= 1) {
    d1 += __shfl_xor(d1, off);
    d2 += __shfl_xor(d2, off);
  }
  if (lane == 0) {
    Wh1[i] = d1;
    Wh2[i] = d2;
    atomicMax(maxkey, fkey(d2));
  }
}

// ---------------- k2: WhTf = bf16(X@W)^T in B-fragment image layout --------
// Image: per 32-j tile jt: 16 units (u = wv*4+nn -> f group) x 64 cells x 16B.
// cell c of unit u: f = (u>>2)*64 + (u&3)*16 + (c&15), j = jt*32 + (c>>4)*8 + e.
__global__ __launch_bounds__(256) void k2_wht(const float* __restrict__ X,
                                              const unsigned short* __restrict__ WTb,
                                              char* __restrict__ WhTf) {
  __shared__ char smem[32768];
  int t = threadIdx.x, wv = t >> 6, lane = t & 63;
  int jb = blockIdx.x * 64;
  int ar = t >> 2;           // row j-in-tile 0..63
  int ac = t & 3;            // k8 group
  int lB = ((t >> 2) & 15) | ((t & 3) << 4);  // staging cell index
  float4 xa, xb;
  uint4 wsr[4];
  f32x4 acc[4][4];
#pragma unroll
  for (int a = 0; a < 4; ++a)
#pragma unroll
    for (int b = 0; b < 4; ++b) acc[a][b] = (f32x4){0.f, 0.f, 0.f, 0.f};

#define K2_LOADS(KC)                                                          \
  do {                                                                        \
    const float* xp = X + (size_t)(jb + ar) * KIN + (KC) + ac * 8;            \
    xa = *(const float4*)xp;                                                  \
    xb = *(const float4*)(xp + 4);                                            \
    wsr[0] = *(const uint4*)(WTb + (size_t)((t >> 2) + 0) * KIN + (KC) + ac * 8);   \
    wsr[1] = *(const uint4*)(WTb + (size_t)((t >> 2) + 64) * KIN + (KC) + ac * 8);  \
    wsr[2] = *(const uint4*)(WTb + (size_t)((t >> 2) + 128) * KIN + (KC) + ac * 8); \
    wsr[3] = *(const uint4*)(WTb + (size_t)((t >> 2) + 192) * KIN + (KC) + ac * 8); \
  } while (0)

  K2_LOADS(0);
  for (int s = 0; s < 16; ++s) {
    uint4 ap;
    ap.x = f2bf(xa.x) | (f2bf(xa.y) << 16);
    ap.y = f2bf(xa.z) | (f2bf(xa.w) << 16);
    ap.z = f2bf(xb.x) | (f2bf(xb.y) << 16);
    ap.w = f2bf(xb.z) | (f2bf(xb.w) << 16);
    __syncthreads();
    *(uint4*)(smem + wv * 1024 + lB * 16) = ap;
#pragma unroll
    for (int p = 0; p < 4; ++p)
      *(uint4*)(smem + 4096 + (wv + p * 4) * 1024 + lB * 16) = wsr[p];
    if (s + 1 < 16) K2_LOADS((s + 1) * 32);
    __syncthreads();
    bf16x8 af[4], bfr[4];
#pragma unroll
    for (int mi = 0; mi < 4; ++mi)
      af[mi] = *(const bf16x8*)(smem + mi * 1024 + lane * 16);
#pragma unroll
    for (int nn = 0; nn < 4; ++nn)
      bfr[nn] = *(const bf16x8*)(smem + 4096 + (wv * 4 + nn) * 1024 + lane * 16);
#pragma unroll
    for (int mi = 0; mi < 4; ++mi)
#pragma unroll
      for (int nn = 0; nn < 4; ++nn)
        acc[mi][nn] = __builtin_amdgcn_mfma_f32_16x16x32_bf16(af[mi], bfr[nn],
                                                              acc[mi][nn], 0, 0, 0);
  }
#undef K2_LOADS
  // Epilogue: build the 2-tile fragment image (32 KB) in LDS, then flat-copy out.
  __syncthreads();
  int q = lane >> 4;
#pragma unroll
  for (int mi = 0; mi < 4; ++mi)
#pragma unroll
    for (int nn = 0; nn < 4; ++nn) {
      int c = ((((mi & 1) << 1) | (q >> 1)) << 4) | (lane & 15);
      char* p = smem + (mi >> 1) * 16384 + (wv * 4 + nn) * 1024 + c * 16 +
                ((q & 1) << 3);
      ushort2 lo, hi;
      lo.x = (unsigned short)f2bf(acc[mi][nn].x);
      lo.y = (unsigned short)f2bf(acc[mi][nn].y);
      hi.x = (unsigned short)f2bf(acc[mi][nn].z);
      hi.y = (unsigned short)f2bf(acc[mi][nn].w);
      *(ushort2*)p = lo;
      *(ushort2*)(p + 4) = hi;
    }
  __syncthreads();
  char* wb = WhTf + (size_t)jb * 512;  // 64 j -> 2 tiles * 16384 B
#pragma unroll
  for (int q2 = 0; q2 < 8; ++q2) {
    uint4 v = *(const uint4*)(smem + q2 * 4096 + t * 16);
    *(uint4*)(wb + q2 * 4096 + t * 16) = v;
  }
}

// ---------------- k3: fused attention weights + PV matmul ----------------
__device__ __forceinline__ uint2 hv4(int4 aq, float4 wq, float wh1, float m,
                                     float enm, float& z) {
  float s0 = wh1 + wq.x, s1 = wh1 + wq.y, s2 = wh1 + wq.z, s3 = wh1 + wq.w;
  s0 = s0 > 0.f ? s0 : 0.2f * s0;
  s1 = s1 > 0.f ? s1 : 0.2f * s1;
  s2 = s2 > 0.f ? s2 : 0.2f * s2;
  s3 = s3 > 0.f ? s3 : 0.2f * s3;
  float w0 = aq.x > 0 ? __expf(s0 - m) : enm;
  float w1 = aq.y > 0 ? __expf(s1 - m) : enm;
  float w2 = aq.z > 0 ? __expf(s2 - m) : enm;
  float w3 = aq.w > 0 ? __expf(s3 - m) : enm;
  unsigned h0 = f2bf(w0), h1 = f2bf(w1), h2 = f2bf(w2), h3 = f2bf(w3);
  z += bf2f(h0) + bf2f(h1) + bf2f(h2) + bf2f(h3);
  uint2 r;
  r.x = h0 | (h1 << 16);
  r.y = h2 | (h3 << 16);
  return r;
}

__global__ __launch_bounds__(256, 4) void k3_attn(
    const int* __restrict__ adj, const char* __restrict__ WhTfB,
    const float* __restrict__ Wh1, const float* __restrict__ Wh2,
    const unsigned* __restrict__ maxkey, float* __restrict__ PVp,
    float* __restrict__ Zp) {
  // buffer: [A: 2 units x 1KB][B: 16 units x 1KB] = 18432 B, double-buffered.
  __shared__ char smem[2 * 18432];
  char* buf0 = smem;
  char* buf1 = smem + 18432;
  int t = threadIdx.x, wv = t >> 6, lane = t & 63;
  int kc = blockIdx.x & 3;
  int ib = blockIdx.x >> 2;  // 0..255
  int ibase = ib * IROWS;
  int jbch = kc * JCHUNK;
  int r0 = t >> 3;           // row in tile 0..31
  int jg = (t & 7) * 4;      // j offset 0..28
  int iglob = ibase + r0;
  float maxwh2 = fkey_dec(*maxkey);
  float wh1 = Wh1[iglob];
  float m = fmaxf(0.f, wh1 + maxwh2);
  float enm = __expf(-m);
  // A-write: unit mi = r0>>4; cell c = (r0&15)|(((t>>1)&3)<<4); XOR-swizzled slot.
  {
  }
  int cA = (r0 & 15) | (((t >> 1) & 3) << 4);
  int slotA = cA ^ (((cA >> 4) & 3) << 1);
  int aoff = (r0 >> 4) * 1024 + slotA * 16 + ((t & 1) << 3);
  int slotR = lane ^ (((lane >> 4) & 3) << 1);

  int4 stA_adj, stB_adj;
  float4 stA_wh2, stB_wh2;
  f32x4 acc[2][4];
#pragma unroll
  for (int a = 0; a < 2; ++a)
#pragma unroll
    for (int b = 0; b < 4; ++b) acc[a][b] = (f32x4){0.f, 0.f, 0.f, 0.f};
  float zacc = 0.f;

#define K3_GLB(SIDX, BUFW)                                                    \
  do {                                                                        \
    int jt_ = kc * (JCHUNK / 32) + (SIDX);                                    \
    const char* gs_ = WhTfB + ((size_t)jt_ << 14) + (wv << 12) + lane * 16;   \
    char* ld_ = (BUFW) + 2048 + (wv << 12);                                   \
    GLDS(gs_, ld_);                                                           \
    GLDS(gs_ + 1024, ld_ + 1024);                                             \
    GLDS(gs_ + 2048, ld_ + 2048);                                             \
    GLDS(gs_ + 3072, ld_ + 3072);                                             \
  } while (0)

#define K3_LD(SIDX, ST)                                                       \
  do {                                                                        \
    int jc_ = jbch + (SIDX) * BKJ;                                            \
    ST##_adj = *(const int4*)(adj + ((size_t)iglob << 13) + jc_ + jg);        \
    ST##_wh2 = *(const float4*)(Wh2 + jc_ + jg);                              \
  } while (0)

#define K3_ITER(S, BUFR, BUFW, STC, STF)                                      \
  do {                                                                        \
    int s_ = (S);                                                             \
    K3_GLB(s_ + 1 < NSTEP ? s_ + 1 : NSTEP - 1, BUFW);                        \
    K3_LD(s_ + 2 < NSTEP ? s_ + 2 : NSTEP - 1, STF);                          \
    bf16x8 af0 = *(const bf16x8*)((BUFR) + slotR * 16);                       \
    bf16x8 af1 = *(const bf16x8*)((BUFR) + 1024 + slotR * 16);                \
    bf16x8 b0 = *(const bf16x8*)((BUFR) + 2048 + (wv * 4 + 0) * 1024 + lane * 16); \
    bf16x8 b1 = *(const bf16x8*)((BUFR) + 2048 + (wv * 4 + 1) * 1024 + lane * 16); \
    bf16x8 b2 = *(const bf16x8*)((BUFR) + 2048 + (wv * 4 + 2) * 1024 + lane * 16); \
    bf16x8 b3 = *(const bf16x8*)((BUFR) + 2048 + (wv * 4 + 3) * 1024 + lane * 16); \
    acc[0][0] = __builtin_amdgcn_mfma_f32_16x16x32_bf16(af0, b0, acc[0][0], 0, 0, 0); \
    acc[0][1] = __builtin_amdgcn_mfma_f32_16x16x32_bf16(af0, b1, acc[0][1], 0, 0, 0); \
    acc[0][2] = __builtin_amdgcn_mfma_f32_16x16x32_bf16(af0, b2, acc[0][2], 0, 0, 0); \
    acc[0][3] = __builtin_amdgcn_mfma_f32_16x16x32_bf16(af0, b3, acc[0][3], 0, 0, 0); \
    acc[1][0] = __builtin_amdgcn_mfma_f32_16x16x32_bf16(af1, b0, acc[1][0], 0, 0, 0); \
    acc[1][1] = __builtin_amdgcn_mfma_f32_16x16x32_bf16(af1, b1, acc[1][1], 0, 0, 0); \
    acc[1][2] = __builtin_amdgcn_mfma_f32_16x16x32_bf16(af1, b2, acc[1][2], 0, 0, 0); \
    acc[1][3] = __builtin_amdgcn_mfma_f32_16x16x32_bf16(af1, b3, acc[1][3], 0, 0, 0); \
    if (s_ + 1 < NSTEP) {                                                     \
      uint2 a_ = hv4(STC##_adj, STC##_wh2, wh1, m, enm, zacc);                \
      *(uint2*)((BUFW) + aoff) = a_;                                          \
    }                                                                         \
    __builtin_amdgcn_sched_barrier(0);                                        \
    asm volatile("s_waitcnt vmcnt(2)");                                       \
    asm volatile("s_waitcnt lgkmcnt(0)");                                     \
    __builtin_amdgcn_s_barrier();                                             \
    __builtin_amdgcn_sched_barrier(0);                                        \
  } while (0)

  // Prologue: B(0)->buf0 (oldest), stage(0)->stA, stage(1)->stB; hv(0)+A(0)->buf0.
  K3_GLB(0, buf0);
  K3_LD(0, stA);
  K3_LD(1, stB);
  {
    uint2 a0 = hv4(stA_adj, stA_wh2, wh1, m, enm, zacc);
    *(uint2*)(buf0 + aoff) = a0;
  }
  __builtin_amdgcn_sched_barrier(0);
  asm volatile("s_waitcnt vmcnt(2)");
  asm volatile("s_waitcnt lgkmcnt(0)");
  __builtin_amdgcn_s_barrier();
  __builtin_amdgcn_sched_barrier(0);

  for (int s2 = 0; s2 < NSTEP; s2 += 2) {
    K3_ITER(s2, buf0, buf1, stB, stA);
    K3_ITER(s2 + 1, buf1, buf0, stA, stB);
  }
#undef K3_ITER
#undef K3_LD
#undef K3_GLB

  // Z partial: 8 threads (t&7) share row r0.
  zacc += __shfl_xor(zacc, 1);
  zacc += __shfl_xor(zacc, 2);
  zacc += __shfl_xor(zacc, 4);
  if ((t & 7) == 0) Zp[(size_t)kc * NR + iglob] = zacc;
#pragma unroll
  for (int mi = 0; mi < 2; ++mi)
#pragma unroll
    for (int nn = 0; nn < 4; ++nn) {
      int f = wv * 64 + nn * 16 + (lane & 15);
      int row0 = ibase + mi * 16 + ((lane >> 4) << 2);
      size_t base = ((size_t)kc * NR + row0) * FOUT + f;
      PVp[base + 0 * FOUT] = acc[mi][nn].x;
      PVp[base + 1 * FOUT] = acc[mi][nn].y;
      PVp[base + 2 * FOUT] = acc[mi][nn].z;
      PVp[base + 3 * FOUT] = acc[mi][nn].w;
    }
}

// ---------------- k4: reduce partials, normalize, relu ----------------
__global__ __launch_bounds__(256) void k4_reduce(const float* __restrict__ PVp,
                                                 const float* __restrict__ Zp,
                                                 float* __restrict__ out) {
  int tid = blockIdx.x * 256 + threadIdx.x;  // 0..524287
  int i = tid >> 6;
  int f4 = (tid & 63) * 4;
  float z = Zp[i] + Zp[NR + i] + Zp[2 * NR + i] + Zp[3 * NR + i];
  float4 a = {0.f, 0.f, 0.f, 0.f};
#pragma unroll
  for (int c = 0; c < KSPLIT; ++c) {
    float4 p = *(const float4*)(PVp + ((size_t)c * NR + i) * FOUT + f4);
    a.x += p.x;
    a.y += p.y;
    a.z += p.z;
    a.w += p.w;
  }
  float inv = 1.f / z;
  float4 r;
  r.x = fmaxf(a.x * inv, 0.f);
  r.y = fmaxf(a.y * inv, 0.f);
  r.z = fmaxf(a.z * inv, 0.f);
  r.w = fmaxf(a.w * inv, 0.f);
  *(float4*)(out + (size_t)i * FOUT + f4) = r;
}

// ---------------- launch ----------------
extern "C" void kernel_launch(void* const* d_in, const int* in_sizes, int n_in,
                              void* d_out, int out_size, void* d_ws,
                              size_t ws_size, hipStream_t stream) {
  const float* X = (const float*)d_in[0];
  const float* W = (const float*)d_in[1];
  const float* W2 = (const float*)d_in[2];
  const int* adj = (const int*)d_in[3];
  float* out = (float*)d_out;
  char* ws = (char*)d_ws;

  const size_t WHT_OFF = 0;                              // fragment image, 4 MB
  const size_t WTB_OFF = (size_t)4 * 1024 * 1024;        // ushort[256*512]
  const size_t W1_OFF = WTB_OFF + 256 * 1024;
  const size_t W2V_OFF = W1_OFF + 2048;
  const size_t WH1_OFF = W2V_OFF + 2048;
  const size_t WH2_OFF = WH1_OFF + 32768;
  const size_t MXK_OFF = WH2_OFF + 32768;
  const size_t ZP_OFF = MXK_OFF + 256;                   // float[4][8192]
  const size_t PV_OFF = ZP_OFF + (size_t)KSPLIT * NR * 4;  // float[4][8192][256]

  char* WhTf = ws + WHT_OFF;
  unsigned short* WTb = (unsigned short*)(ws + WTB_OFF);
  float* w1 = (float*)(ws + W1_OFF);
  float* w2 = (float*)(ws + W2V_OFF);
  float* Wh1 = (float*)(ws + WH1_OFF);
  float* Wh2 = (float*)(ws + WH2_OFF);
  unsigned* maxkey = (unsigned*)(ws + MXK_OFF);
  float* Zp = (float*)(ws + ZP_OFF);
  float* PVp = (float*)(ws + PV_OFF);

  hipMemsetAsync(maxkey, 0, 4, stream);
  k0_prep<<<128, 256, 0, stream>>>(W, W2, w1, w2, WTb);
  k1_wh12<<<2048, 256, 0, stream>>>(X, w1, w2, Wh1, Wh2, maxkey);
  k2_wht<<<128, 256, 0, stream>>>(X, WTb, WhTf);
  k3_attn<<<1024, 256, 0, stream>>>(adj, WhTf, Wh1, Wh2, maxkey, PVp, Zp);
  k4_reduce<<<2048, 256, 0, stream>>>(PVp, Zp, out);
}

// Round 3
// 142.584 us; speedup vs baseline: 2.4684x; 1.7648x over previous
//
#include <hip/hip_runtime.h>
#include <cstdint>
#include <cstddef>

// GraphAttentionLayer: N=8192, IN=512, OUT=256
//  k0: w1=W@W2[:256], w2=W@W2[256:], WTbf = bf16(W^T) in MFMA-B fragment image
//  k1: Wh1 = X@w1, Wh2 = X@w2 (exact fp32)
//  k1b: maxwh2 = max(Wh2) (single block, no atomics)
//  k2: WhTf = bf16(X@W)^T fragment image [jt 256][16 units][64 cells][16B]
//  k3: fused mask+lrelu+softmax-weights + (attention @ Wh). 512 thr, BKJ=64,
//      KSPLIT=2 -> 512 blocks = 2/CU. dbuf LDS + counted vmcnt + GLDS B-staging.
//  k4: reduce 2 partials, divide by Z, relu
#define NR 8192
#define FOUT 256
#define KIN 512
#define KSPLIT 2
#define JCHUNK (NR / KSPLIT)  // 4096
#define BKJ 64
#define NSTEP (JCHUNK / BKJ)  // 64
#define IROWS 32

typedef __attribute__((ext_vector_type(8))) short bf16x8;
typedef __attribute__((ext_vector_type(4))) float f32x4;

__device__ __forceinline__ unsigned f2bf(float x) {
  unsigned u = __float_as_uint(x);
  u += 0x7fffu + ((u >> 16) & 1u);
  return u >> 16;
}
__device__ __forceinline__ float bf2f(unsigned h) {
  return __uint_as_float(h << 16);
}

#define GLDS(g, l)                                                            \
  __builtin_amdgcn_global_load_lds(                                           \
      (const __attribute__((address_space(1))) unsigned int*)(g),             \
      (__attribute__((address_space(3))) unsigned int*)(l), 16, 0, 0)

// ---------------- k0: w1, w2, WTbf (B-fragment image) ----------------
__global__ __launch_bounds__(256) void k0_prep(const float* __restrict__ W,
                                               const float* __restrict__ W2,
                                               float* __restrict__ w1,
                                               float* __restrict__ w2,
                                               char* __restrict__ WTbf) {
  int wv = threadIdx.x >> 6, lane = threadIdx.x & 63;
  int k = blockIdx.x * 4 + wv;  // 0..511
  int f4 = lane * 4;
  float4 wr = *(const float4*)(W + (size_t)k * FOUT + f4);
  float4 a = *(const float4*)(W2 + f4);
  float4 b = *(const float4*)(W2 + FOUT + f4);
  float d1 = wr.x * a.x + wr.y * a.y + wr.z * a.z + wr.w * a.w;
  float d2 = wr.x * b.x + wr.y * b.y + wr.z * b.z + wr.w * b.w;
#pragma unroll
  for (int off = 32; off; off >>= 1) {
    d1 += __shfl_xor(d1, off);
    d2 += __shfl_xor(d2, off);
  }
  if (lane == 0) {
    w1[k] = d1;
    w2[k] = d2;
  }
  int kt = k >> 5, kl = k & 31;
  float wv4[4] = {wr.x, wr.y, wr.z, wr.w};
#pragma unroll
  for (int ff = 0; ff < 4; ++ff) {
    int f = f4 + ff;
    size_t addr = (size_t)kt * 16384 + (f >> 4) * 1024 +
                  (((f & 15) | (((kl >> 3) & 3) << 4)) * 16) + (kl & 7) * 2;
    *(unsigned short*)(WTbf + addr) = (unsigned short)f2bf(wv4[ff]);
  }
}

// ---------------- k1: Wh1, Wh2 (exact fp32, no atomics) ----------------
__global__ __launch_bounds__(256) void k1_wh12(const float* __restrict__ X,
                                               const float* __restrict__ w1,
                                               const float* __restrict__ w2,
                                               float* __restrict__ Wh1,
                                               float* __restrict__ Wh2) {
  int wv = threadIdx.x >> 6, lane = threadIdx.x & 63;
  int i = blockIdx.x * 4 + wv;  // 0..8191
  const float* xp = X + (size_t)i * KIN + lane * 8;
  float4 x0 = *(const float4*)(xp);
  float4 x1 = *(const float4*)(xp + 4);
  float4 a0 = *(const float4*)(w1 + lane * 8);
  float4 a1 = *(const float4*)(w1 + lane * 8 + 4);
  float4 b0 = *(const float4*)(w2 + lane * 8);
  float4 b1 = *(const float4*)(w2 + lane * 8 + 4);
  float d1 = x0.x * a0.x + x0.y * a0.y + x0.z * a0.z + x0.w * a0.w +
             x1.x * a1.x + x1.y * a1.y + x1.z * a1.z + x1.w * a1.w;
  float d2 = x0.x * b0.x + x0.y * b0.y + x0.z * b0.z + x0.w * b0.w +
             x1.x * b1.x + x1.y * b1.y + x1.z * b1.z + x1.w * b1.w;
#pragma unroll
  for (int off = 32; off; off >>= 1) {
    d1 += __shfl_xor(d1, off);
    d2 += __shfl_xor(d2, off);
  }
  if (lane == 0) {
    Wh1[i] = d1;
    Wh2[i] = d2;
  }
}

// ---------------- k1b: max(Wh2), single block ----------------
__global__ __launch_bounds__(256) void k1b_max(const float* __restrict__ Wh2,
                                               float* __restrict__ maxwh2) {
  int t = threadIdx.x;
  float m = -1e30f;
#pragma unroll
  for (int b = 0; b < 8; ++b) {
    float4 v = *(const float4*)(Wh2 + b * 1024 + t * 4);
    m = fmaxf(m, fmaxf(fmaxf(v.x, v.y), fmaxf(v.z, v.w)));
  }
#pragma unroll
  for (int off = 32; off; off >>= 1) m = fmaxf(m, __shfl_xor(m, off));
  __shared__ float red[4];
  if ((t & 63) == 0) red[t >> 6] = m;
  __syncthreads();
  if (t == 0) *maxwh2 = fmaxf(fmaxf(red[0], red[1]), fmaxf(red[2], red[3]));
}

// ---------------- k2: WhTf fragment image, 256 blocks x 32 j ----------------
__global__ __launch_bounds__(256) void k2_wht(const float* __restrict__ X,
                                              const char* __restrict__ WTbf,
                                              char* __restrict__ WhTf) {
  // buffer: [A 2KB][B 16KB] = 18432, double-buffered
  __shared__ char smem[2 * 18432];
  char* buf0 = smem;
  char* buf1 = smem + 18432;
  int t = threadIdx.x, wv = t >> 6, lane = t & 63;
  int jb = blockIdx.x * 32;
  int jr = t >> 3, koff = (t & 7) * 4;
  {
  }
  int cA = (jr & 15) | (((koff >> 3) & 3) << 4);
  int swA = cA ^ (((cA >> 4) & 3) << 2);
  int aoff = (jr >> 4) * 1024 + swA * 16 + ((koff & 4) << 1);
  int slotR = lane ^ (((lane >> 4) & 3) << 2);
  const float* xrow = X + (size_t)(jb + jr) * KIN + koff;

  float4 st0, st1, st2, st3;
  f32x4 acc[2][4];
#pragma unroll
  for (int a = 0; a < 2; ++a)
#pragma unroll
    for (int b = 0; b < 4; ++b) acc[a][b] = (f32x4){0.f, 0.f, 0.f, 0.f};

#define K2_GLB(KT, BUFW)                                                      \
  do {                                                                        \
    const char* gs_ = WTbf + ((size_t)(KT) << 14) + (wv << 12) + lane * 16;   \
    char* ld_ = (BUFW) + 2048 + (wv << 12);                                   \
    GLDS(gs_, ld_);                                                           \
    GLDS(gs_ + 1024, ld_ + 1024);                                             \
    GLDS(gs_ + 2048, ld_ + 2048);                                             \
    GLDS(gs_ + 3072, ld_ + 3072);                                             \
  } while (0)

#define K2_LDX(KT, ST) (ST) = *(const float4*)(xrow + (KT) * 32)

#define K2_AGEN(ST, BUFW)                                                     \
  do {                                                                        \
    uint2 a_;                                                                 \
    a_.x = f2bf((ST).x) | (f2bf((ST).y) << 16);                               \
    a_.y = f2bf((ST).z) | (f2bf((ST).w) << 16);                               \
    *(uint2*)((BUFW) + aoff) = a_;                                            \
  } while (0)

#define K2_ITER(S, BUFR, BUFW, STC, STF)                                      \
  do {                                                                        \
    int s_ = (S);                                                             \
    if (s_ + 1 < 16) K2_GLB(s_ + 1, BUFW);                                    \
    K2_LDX((s_ + 3 < 16) ? s_ + 3 : 15, STF);                                 \
    if (s_ + 1 < 16) K2_AGEN(STC, BUFW);                                      \
    bf16x8 a0 = *(const bf16x8*)((BUFR) + slotR * 16);                        \
    bf16x8 a1 = *(const bf16x8*)((BUFR) + 1024 + slotR * 16);                 \
    bf16x8 b0 = *(const bf16x8*)((BUFR) + 2048 + (wv * 4 + 0) * 1024 + lane * 16); \
    bf16x8 b1 = *(const bf16x8*)((BUFR) + 2048 + (wv * 4 + 1) * 1024 + lane * 16); \
    bf16x8 b2 = *(const bf16x8*)((BUFR) + 2048 + (wv * 4 + 2) * 1024 + lane * 16); \
    bf16x8 b3 = *(const bf16x8*)((BUFR) + 2048 + (wv * 4 + 3) * 1024 + lane * 16); \
    acc[0][0] = __builtin_amdgcn_mfma_f32_16x16x32_bf16(a0, b0, acc[0][0], 0, 0, 0); \
    acc[0][1] = __builtin_amdgcn_mfma_f32_16x16x32_bf16(a0, b1, acc[0][1], 0, 0, 0); \
    acc[0][2] = __builtin_amdgcn_mfma_f32_16x16x32_bf16(a0, b2, acc[0][2], 0, 0, 0); \
    acc[0][3] = __builtin_amdgcn_mfma_f32_16x16x32_bf16(a0, b3, acc[0][3], 0, 0, 0); \
    acc[1][0] = __builtin_amdgcn_mfma_f32_16x16x32_bf16(a1, b0, acc[1][0], 0, 0, 0); \
    acc[1][1] = __builtin_amdgcn_mfma_f32_16x16x32_bf16(a1, b1, acc[1][1], 0, 0, 0); \
    acc[1][2] = __builtin_amdgcn_mfma_f32_16x16x32_bf16(a1, b2, acc[1][2], 0, 0, 0); \
    acc[1][3] = __builtin_amdgcn_mfma_f32_16x16x32_bf16(a1, b3, acc[1][3], 0, 0, 0); \
    __builtin_amdgcn_sched_barrier(0);                                        \
    asm volatile("s_waitcnt vmcnt(1)");                                       \
    asm volatile("s_waitcnt lgkmcnt(0)");                                     \
    __builtin_amdgcn_s_barrier();                                             \
    __builtin_amdgcn_sched_barrier(0);                                        \
  } while (0)

  // Prologue
  K2_GLB(0, buf0);
  K2_LDX(0, st0);
  K2_LDX(1, st1);
  K2_LDX(2, st2);
  K2_AGEN(st0, buf0);
  __builtin_amdgcn_sched_barrier(0);
  asm volatile("s_waitcnt vmcnt(2)");
  asm volatile("s_waitcnt lgkmcnt(0)");
  __builtin_amdgcn_s_barrier();
  __builtin_amdgcn_sched_barrier(0);

  for (int s4 = 0; s4 < 16; s4 += 4) {
    K2_ITER(s4 + 0, buf0, buf1, st1, st3);
    K2_ITER(s4 + 1, buf1, buf0, st2, st0);
    K2_ITER(s4 + 2, buf0, buf1, st3, st1);
    K2_ITER(s4 + 3, buf1, buf0, st0, st2);
  }
#undef K2_ITER
#undef K2_AGEN
#undef K2_LDX
#undef K2_GLB

  // Epilogue: gather fragment image for this 32-j tile into buf0 B-area, copy.
  int q = lane >> 4;
#pragma unroll
  for (int mi = 0; mi < 2; ++mi)
#pragma unroll
    for (int nn = 0; nn < 4; ++nn) {
      int u2 = wv * 4 + nn;
      int cell = (lane & 15) | ((((mi * 2) + (q >> 1)) & 3) << 4);
      uint2 v;
      v.x = f2bf(acc[mi][nn].x) | (f2bf(acc[mi][nn].y) << 16);
      v.y = f2bf(acc[mi][nn].z) | (f2bf(acc[mi][nn].w) << 16);
      *(uint2*)(buf0 + 2048 + u2 * 1024 + cell * 16 + ((q & 1) << 3)) = v;
    }
  __syncthreads();
  char* wb = WhTf + (size_t)blockIdx.x * 16384;
#pragma unroll
  for (int q2 = 0; q2 < 4; ++q2) {
    uint4 v = *(const uint4*)(buf0 + 2048 + q2 * 4096 + t * 16);
    *(uint4*)(wb + q2 * 4096 + t * 16) = v;
  }
}

// ---------------- k3: fused attention weights + PV matmul ----------------
__device__ __forceinline__ uint2 hv4(int4 aq, float4 wq, float wh1, float m,
                                     float enm, float& z) {
  float s0 = wh1 + wq.x, s1 = wh1 + wq.y, s2 = wh1 + wq.z, s3 = wh1 + wq.w;
  s0 = s0 > 0.f ? s0 : 0.2f * s0;
  s1 = s1 > 0.f ? s1 : 0.2f * s1;
  s2 = s2 > 0.f ? s2 : 0.2f * s2;
  s3 = s3 > 0.f ? s3 : 0.2f * s3;
  float w0 = aq.x > 0 ? __expf(s0 - m) : enm;
  float w1 = aq.y > 0 ? __expf(s1 - m) : enm;
  float w2 = aq.z > 0 ? __expf(s2 - m) : enm;
  float w3 = aq.w > 0 ? __expf(s3 - m) : enm;
  unsigned h0 = f2bf(w0), h1 = f2bf(w1), h2 = f2bf(w2), h3 = f2bf(w3);
  z += bf2f(h0) + bf2f(h1) + bf2f(h2) + bf2f(h3);
  uint2 r;
  r.x = h0 | (h1 << 16);
  r.y = h2 | (h3 << 16);
  return r;
}

__global__ __launch_bounds__(512, 4) void k3_attn(
    const int* __restrict__ adj, const char* __restrict__ WhTf,
    const float* __restrict__ Wh1, const float* __restrict__ Wh2,
    const float* __restrict__ maxptr, float* __restrict__ PVp,
    float* __restrict__ Zp) {
  // buffer: [A: 4 units x 1KB][B: 2 tiles x 16KB] = 36864, double-buffered
  __shared__ char smem[2 * 36864];
  char* buf0 = smem;
  char* buf1 = smem + 36864;
  int t = threadIdx.x, wv = t >> 6, lane = t & 63;
  int kc = blockIdx.x & 1;
  int ib = blockIdx.x >> 1;  // 0..255
  int ibase = ib * IROWS;
  int jbch = kc * JCHUNK;
  int r0 = t >> 4;           // row in tile 0..31
  int jg = (t & 15) * 4;     // j offset 0..60
  int iglob = ibase + r0;
  float maxwh2 = *maxptr;
  float wh1 = Wh1[iglob];
  float m = fmaxf(0.f, wh1 + maxwh2);
  float enm = __expf(-m);
  int cA = (r0 & 15) | (((jg >> 3) & 3) << 4);
  int swA = cA ^ (((cA >> 4) & 3) << 2);
  int aoff = ((r0 >> 4) * 2 + (jg >> 5)) * 1024 + swA * 16 + ((jg & 4) << 1);
  int slotR = lane ^ (((lane >> 4) & 3) << 2);
  const int* adjrow = adj + ((size_t)iglob << 13) + jbch + jg;
  const float* wh2p = Wh2 + jbch + jg;

  int4 st0_adj, st1_adj, st2_adj, st3_adj;
  float4 st0_wh2, st1_wh2, st2_wh2, st3_wh2;
  f32x4 acc[2][2];
#pragma unroll
  for (int a = 0; a < 2; ++a)
#pragma unroll
    for (int b = 0; b < 2; ++b) acc[a][b] = (f32x4){0.f, 0.f, 0.f, 0.f};
  float zacc = 0.f;

#define K3_GLB(SIDX, BUFW)                                                    \
  do {                                                                        \
    int jt_ = kc * 128 + (SIDX) * 2;                                          \
    const char* gs_ = WhTf + ((size_t)jt_ << 14) + (wv << 12) + lane * 16;    \
    char* ld_ = (BUFW) + 4096 + (wv << 12);                                   \
    GLDS(gs_, ld_);                                                           \
    GLDS(gs_ + 1024, ld_ + 1024);                                             \
    GLDS(gs_ + 2048, ld_ + 2048);                                             \
    GLDS(gs_ + 3072, ld_ + 3072);                                             \
  } while (0)

#define K3_LD(SIDX, ST)                                                       \
  do {                                                                        \
    ST##_adj = *(const int4*)(adjrow + (SIDX)*BKJ);                           \
    ST##_wh2 = *(const float4*)(wh2p + (SIDX)*BKJ);                           \
  } while (0)

#define K3_ITER(S, BUFR, BUFW, STC, STF)                                      \
  do {                                                                        \
    int s_ = (S);                                                             \
    if (s_ + 1 < NSTEP) K3_GLB(s_ + 1, BUFW);                                 \
    K3_LD((s_ + 3 < NSTEP) ? s_ + 3 : NSTEP - 1, STF);                        \
    if (s_ + 1 < NSTEP) {                                                     \
      uint2 a_ = hv4(STC##_adj, STC##_wh2, wh1, m, enm, zacc);                \
      *(uint2*)((BUFW) + aoff) = a_;                                          \
    }                                                                         \
    {                                                                         \
      const char* br_ = (BUFR);                                               \
      bf16x8 a0_ = *(const bf16x8*)(br_ + 0 * 1024 + slotR * 16);             \
      bf16x8 a1_ = *(const bf16x8*)(br_ + 2 * 1024 + slotR * 16);             \
      bf16x8 b0_ = *(const bf16x8*)(br_ + 4096 + (wv * 2 + 0) * 1024 + lane * 16); \
      bf16x8 b1_ = *(const bf16x8*)(br_ + 4096 + (wv * 2 + 1) * 1024 + lane * 16); \
      acc[0][0] = __builtin_amdgcn_mfma_f32_16x16x32_bf16(a0_, b0_, acc[0][0], 0, 0, 0); \
      acc[0][1] = __builtin_amdgcn_mfma_f32_16x16x32_bf16(a0_, b1_, acc[0][1], 0, 0, 0); \
      acc[1][0] = __builtin_amdgcn_mfma_f32_16x16x32_bf16(a1_, b0_, acc[1][0], 0, 0, 0); \
      acc[1][1] = __builtin_amdgcn_mfma_f32_16x16x32_bf16(a1_, b1_, acc[1][1], 0, 0, 0); \
      a0_ = *(const bf16x8*)(br_ + 1 * 1024 + slotR * 16);                    \
      a1_ = *(const bf16x8*)(br_ + 3 * 1024 + slotR * 16);                    \
      b0_ = *(const bf16x8*)(br_ + 4096 + 16384 + (wv * 2 + 0) * 1024 + lane * 16); \
      b1_ = *(const bf16x8*)(br_ + 4096 + 16384 + (wv * 2 + 1) * 1024 + lane * 16); \
      acc[0][0] = __builtin_amdgcn_mfma_f32_16x16x32_bf16(a0_, b0_, acc[0][0], 0, 0, 0); \
      acc[0][1] = __builtin_amdgcn_mfma_f32_16x16x32_bf16(a0_, b1_, acc[0][1], 0, 0, 0); \
      acc[1][0] = __builtin_amdgcn_mfma_f32_16x16x32_bf16(a1_, b0_, acc[1][0], 0, 0, 0); \
      acc[1][1] = __builtin_amdgcn_mfma_f32_16x16x32_bf16(a1_, b1_, acc[1][1], 0, 0, 0); \
    }                                                                         \
    __builtin_amdgcn_sched_barrier(0);                                        \
    asm volatile("s_waitcnt vmcnt(2)");                                       \
    asm volatile("s_waitcnt lgkmcnt(0)");                                     \
    __builtin_amdgcn_s_barrier();                                             \
    __builtin_amdgcn_sched_barrier(0);                                        \
  } while (0)

  // Prologue: GLDS(0)->buf0; adj 0,1,2 -> st0,st1,st2; A(0)->buf0.
  K3_GLB(0, buf0);
  K3_LD(0, st0);
  K3_LD(1, st1);
  K3_LD(2, st2);
  {
    uint2 a_ = hv4(st0_adj, st0_wh2, wh1, m, enm, zacc);
    *(uint2*)(buf0 + aoff) = a_;
  }
  __builtin_amdgcn_sched_barrier(0);
  asm volatile("s_waitcnt vmcnt(4)");
  asm volatile("s_waitcnt lgkmcnt(0)");
  __builtin_amdgcn_s_barrier();
  __builtin_amdgcn_sched_barrier(0);

  for (int s4 = 0; s4 < NSTEP; s4 += 4) {
    K3_ITER(s4 + 0, buf0, buf1, st1, st3);
    K3_ITER(s4 + 1, buf1, buf0, st2, st0);
    K3_ITER(s4 + 2, buf0, buf1, st3, st1);
    K3_ITER(s4 + 3, buf1, buf0, st0, st2);
  }
#undef K3_ITER
#undef K3_LD
#undef K3_GLB

  // Z reduce over the 16 threads sharing row r0.
  zacc += __shfl_xor(zacc, 1);
  zacc += __shfl_xor(zacc, 2);
  zacc += __shfl_xor(zacc, 4);
  zacc += __shfl_xor(zacc, 8);
  if ((t & 15) == 0) Zp[(size_t)kc * NR + iglob] = zacc;
#pragma unroll
  for (int rf = 0; rf < 2; ++rf)
#pragma unroll
    for (int un = 0; un < 2; ++un) {
      int f = wv * 32 + un * 16 + (lane & 15);
      int row0 = ibase + rf * 16 + ((lane >> 4) << 2);
      size_t base = ((size_t)kc * NR + row0) * FOUT + f;
      PVp[base + 0 * FOUT] = acc[rf][un].x;
      PVp[base + 1 * FOUT] = acc[rf][un].y;
      PVp[base + 2 * FOUT] = acc[rf][un].z;
      PVp[base + 3 * FOUT] = acc[rf][un].w;
    }
}

// ---------------- k4: reduce partials, normalize, relu ----------------
__global__ __launch_bounds__(256) void k4_reduce(const float* __restrict__ PVp,
                                                 const float* __restrict__ Zp,
                                                 float* __restrict__ out) {
  int tid = blockIdx.x * 256 + threadIdx.x;  // 0..524287
  int i = tid >> 6;
  int f4 = (tid & 63) * 4;
  float z = Zp[i] + Zp[NR + i];
  float4 p0 = *(const float4*)(PVp + (size_t)i * FOUT + f4);
  float4 p1 = *(const float4*)(PVp + ((size_t)NR + i) * FOUT + f4);
  float inv = 1.f / z;
  float4 r;
  r.x = fmaxf((p0.x + p1.x) * inv, 0.f);
  r.y = fmaxf((p0.y + p1.y) * inv, 0.f);
  r.z = fmaxf((p0.z + p1.z) * inv, 0.f);
  r.w = fmaxf((p0.w + p1.w) * inv, 0.f);
  *(float4*)(out + (size_t)i * FOUT + f4) = r;
}

// ---------------- launch ----------------
extern "C" void kernel_launch(void* const* d_in, const int* in_sizes, int n_in,
                              void* d_out, int out_size, void* d_ws,
                              size_t ws_size, hipStream_t stream) {
  const float* X = (const float*)d_in[0];
  const float* W = (const float*)d_in[1];
  const float* W2 = (const float*)d_in[2];
  const int* adj = (const int*)d_in[3];
  float* out = (float*)d_out;
  char* ws = (char*)d_ws;

  const size_t WHT_OFF = 0;                               // 4 MB fragment image
  const size_t WTBF_OFF = (size_t)4 * 1024 * 1024;        // 256 KB
  const size_t W1_OFF = WTBF_OFF + 256 * 1024;
  const size_t W2V_OFF = W1_OFF + 2048;
  const size_t WH1_OFF = W2V_OFF + 2048;
  const size_t WH2_OFF = WH1_OFF + 32768;
  const size_t MXK_OFF = WH2_OFF + 32768;
  const size_t ZP_OFF = MXK_OFF + 256;                    // float[2][8192]
  const size_t PV_OFF = ZP_OFF + (size_t)KSPLIT * NR * 4; // float[2][8192][256]

  char* WhTf = ws + WHT_OFF;
  char* WTbf = ws + WTBF_OFF;
  float* w1 = (float*)(ws + W1_OFF);
  float* w2 = (float*)(ws + W2V_OFF);
  float* Wh1 = (float*)(ws + WH1_OFF);
  float* Wh2 = (float*)(ws + WH2_OFF);
  float* maxwh2 = (float*)(ws + MXK_OFF);
  float* Zp = (float*)(ws + ZP_OFF);
  float* PVp = (float*)(ws + PV_OFF);

  k0_prep<<<128, 256, 0, stream>>>(W, W2, w1, w2, WTbf);
  k1_wh12<<<2048, 256, 0, stream>>>(X, w1, w2, Wh1, Wh2);
  k1b_max<<<1, 256, 0, stream>>>(Wh2, maxwh2);
  k2_wht<<<256, 256, 0, stream>>>(X, WTbf, WhTf);
  k3_attn<<<512, 512, 0, stream>>>(adj, WhTf, Wh1, Wh2, maxwh2, PVp, Zp);
  k4_reduce<<<2048, 256, 0, stream>>>(PVp, Zp, out);
}

// Round 4
// 139.362 us; speedup vs baseline: 2.5255x; 1.0231x over previous
//
#include <hip/hip_runtime.h>
#include <cstdint>
#include <cstddef>

// GraphAttentionLayer: N=8192, IN=512, OUT=256
//  k0: w1=W@W2[:256], w2=W@W2[256:], WTbf = bf16(W^T) fragment image, maxkey=0
//  k2f: WhTf = bf16(X@W)^T fragment image  +  Wh1/Wh2 = X@w1/w2 (exact fp32,
//       fused into the same X stream)  +  per-block atomicMax(fkey(Wh2))
//  k3: fused mask+lrelu+softmax-weights + (attention @ Wh). 512 thr, BKJ=64,
//      KSPLIT=2 -> 512 blocks = 2/CU. dbuf LDS + counted vmcnt + GLDS B-staging.
//  k4: reduce 2 partials, divide by Z, relu
#define NR 8192
#define FOUT 256
#define KIN 512
#define KSPLIT 2
#define JCHUNK (NR / KSPLIT)  // 4096
#define BKJ 64
#define NSTEP (JCHUNK / BKJ)  // 64
#define IROWS 32

typedef __attribute__((ext_vector_type(8))) short bf16x8;
typedef __attribute__((ext_vector_type(4))) float f32x4;

__device__ __forceinline__ unsigned f2bf(float x) {
  unsigned u = __float_as_uint(x);
  u += 0x7fffu + ((u >> 16) & 1u);
  return u >> 16;
}
__device__ __forceinline__ float bf2f(unsigned h) {
  return __uint_as_float(h << 16);
}
// monotone float<->uint key for atomicMax (0 == -inf sentinel)
__device__ __forceinline__ unsigned fkey(float x) {
  unsigned u = __float_as_uint(x);
  return (u & 0x80000000u) ? ~u : (u | 0x80000000u);
}
__device__ __forceinline__ float fkey_dec(unsigned k) {
  return __uint_as_float((k & 0x80000000u) ? (k ^ 0x80000000u) : ~k);
}

#define GLDS(g, l)                                                            \
  __builtin_amdgcn_global_load_lds(                                           \
      (const __attribute__((address_space(1))) unsigned int*)(g),             \
      (__attribute__((address_space(3))) unsigned int*)(l), 16, 0, 0)

// ---------------- k0: w1, w2, WTbf (B-fragment image), maxkey init ---------
__global__ __launch_bounds__(256) void k0_prep(const float* __restrict__ W,
                                               const float* __restrict__ W2,
                                               float* __restrict__ w1,
                                               float* __restrict__ w2,
                                               char* __restrict__ WTbf,
                                               unsigned* __restrict__ maxkey) {
  if (blockIdx.x == 0 && threadIdx.x == 0) *maxkey = 0u;
  int wv = threadIdx.x >> 6, lane = threadIdx.x & 63;
  int k = blockIdx.x * 4 + wv;  // 0..511
  int f4 = lane * 4;
  float4 wr = *(const float4*)(W + (size_t)k * FOUT + f4);
  float4 a = *(const float4*)(W2 + f4);
  float4 b = *(const float4*)(W2 + FOUT + f4);
  float d1 = wr.x * a.x + wr.y * a.y + wr.z * a.z + wr.w * a.w;
  float d2 = wr.x * b.x + wr.y * b.y + wr.z * b.z + wr.w * b.w;
#pragma unroll
  for (int off = 32; off; off >>= 1) {
    d1 += __shfl_xor(d1, off);
    d2 += __shfl_xor(d2, off);
  }
  if (lane == 0) {
    w1[k] = d1;
    w2[k] = d2;
  }
  int kt = k >> 5, kl = k & 31;
  float wv4[4] = {wr.x, wr.y, wr.z, wr.w};
#pragma unroll
  for (int ff = 0; ff < 4; ++ff) {
    int f = f4 + ff;
    size_t addr = (size_t)kt * 16384 + (f >> 4) * 1024 +
                  (((f & 15) | (((kl >> 3) & 3) << 4)) * 16) + (kl & 7) * 2;
    *(unsigned short*)(WTbf + addr) = (unsigned short)f2bf(wv4[ff]);
  }
}

// ---------------- k2f: WhTf fragment image + Wh1/Wh2 + maxkey --------------
__global__ __launch_bounds__(256) void k2_fused(
    const float* __restrict__ X, const char* __restrict__ WTbf,
    const float* __restrict__ w1, const float* __restrict__ w2,
    char* __restrict__ WhTf, float* __restrict__ Wh1, float* __restrict__ Wh2,
    unsigned* __restrict__ maxkey) {
  // [dbuf: 2 x (A 2KB + B 16KB)][w-slices 4KB]
  __shared__ char smem[2 * 18432 + 4096];
  char* buf0 = smem;
  char* buf1 = smem + 18432;
  char* wlds = smem + 2 * 18432;  // w1 floats [0,2048), w2 floats [2048,4096)
  int t = threadIdx.x, wv = t >> 6, lane = t & 63;
  int jb = blockIdx.x * 32;
  int jr = t >> 3, koff = (t & 7) * 4;
  int cA = (jr & 15) | (((koff >> 3) & 3) << 4);
  int swA = cA ^ (((cA >> 4) & 3) << 2);
  int aoff = (jr >> 4) * 1024 + swA * 16 + ((koff & 4) << 1);
  int slotR = lane ^ (((lane >> 4) & 3) << 2);
  const float* xrow = X + (size_t)(jb + jr) * KIN + koff;

  // Stage w1/w2 into LDS (reads via lgkm, so they don't pollute vmcnt).
  {
    float2 a_ = *(const float2*)(w1 + t * 2);
    float2 b_ = *(const float2*)(w2 + t * 2);
    *(float2*)(wlds + t * 8) = a_;
    *(float2*)(wlds + 2048 + t * 8) = b_;
  }
  __syncthreads();

  float4 st0, st1, st2, st3;
  float d1 = 0.f, d2 = 0.f;
  f32x4 acc[2][4];
#pragma unroll
  for (int a = 0; a < 2; ++a)
#pragma unroll
    for (int b = 0; b < 4; ++b) acc[a][b] = (f32x4){0.f, 0.f, 0.f, 0.f};

#define K2_GLB(KT, BUFW)                                                      \
  do {                                                                        \
    const char* gs_ = WTbf + ((size_t)(KT) << 14) + (wv << 12) + lane * 16;   \
    char* ld_ = (BUFW) + 2048 + (wv << 12);                                   \
    GLDS(gs_, ld_);                                                           \
    GLDS(gs_ + 1024, ld_ + 1024);                                             \
    GLDS(gs_ + 2048, ld_ + 2048);                                             \
    GLDS(gs_ + 3072, ld_ + 3072);                                             \
  } while (0)

#define K2_LDX(KT, ST) (ST) = *(const float4*)(xrow + (KT) * 32)

#define K2_AGEN(ST, BUFW, SNUM)                                               \
  do {                                                                        \
    uint2 a_;                                                                 \
    a_.x = f2bf((ST).x) | (f2bf((ST).y) << 16);                               \
    a_.y = f2bf((ST).z) | (f2bf((ST).w) << 16);                               \
    *(uint2*)((BUFW) + aoff) = a_;                                            \
    float4 wa_ = *(const float4*)(wlds + ((SNUM)*32 + koff) * 4);             \
    float4 wb_ = *(const float4*)(wlds + 2048 + ((SNUM)*32 + koff) * 4);      \
    d1 += (ST).x * wa_.x + (ST).y * wa_.y + (ST).z * wa_.z + (ST).w * wa_.w;  \
    d2 += (ST).x * wb_.x + (ST).y * wb_.y + (ST).z * wb_.z + (ST).w * wb_.w;  \
  } while (0)

#define K2_ITER(S, BUFR, BUFW, STC, STF)                                      \
  do {                                                                        \
    int s_ = (S);                                                             \
    if (s_ + 1 < 16) K2_GLB(s_ + 1, BUFW);                                    \
    K2_LDX((s_ + 3 < 16) ? s_ + 3 : 15, STF);                                 \
    if (s_ + 1 < 16) K2_AGEN(STC, BUFW, s_ + 1);                              \
    bf16x8 a0 = *(const bf16x8*)((BUFR) + slotR * 16);                        \
    bf16x8 a1 = *(const bf16x8*)((BUFR) + 1024 + slotR * 16);                 \
    bf16x8 b0 = *(const bf16x8*)((BUFR) + 2048 + (wv * 4 + 0) * 1024 + lane * 16); \
    bf16x8 b1 = *(const bf16x8*)((BUFR) + 2048 + (wv * 4 + 1) * 1024 + lane * 16); \
    bf16x8 b2 = *(const bf16x8*)((BUFR) + 2048 + (wv * 4 + 2) * 1024 + lane * 16); \
    bf16x8 b3 = *(const bf16x8*)((BUFR) + 2048 + (wv * 4 + 3) * 1024 + lane * 16); \
    acc[0][0] = __builtin_amdgcn_mfma_f32_16x16x32_bf16(a0, b0, acc[0][0], 0, 0, 0); \
    acc[0][1] = __builtin_amdgcn_mfma_f32_16x16x32_bf16(a0, b1, acc[0][1], 0, 0, 0); \
    acc[0][2] = __builtin_amdgcn_mfma_f32_16x16x32_bf16(a0, b2, acc[0][2], 0, 0, 0); \
    acc[0][3] = __builtin_amdgcn_mfma_f32_16x16x32_bf16(a0, b3, acc[0][3], 0, 0, 0); \
    acc[1][0] = __builtin_amdgcn_mfma_f32_16x16x32_bf16(a1, b0, acc[1][0], 0, 0, 0); \
    acc[1][1] = __builtin_amdgcn_mfma_f32_16x16x32_bf16(a1, b1, acc[1][1], 0, 0, 0); \
    acc[1][2] = __builtin_amdgcn_mfma_f32_16x16x32_bf16(a1, b2, acc[1][2], 0, 0, 0); \
    acc[1][3] = __builtin_amdgcn_mfma_f32_16x16x32_bf16(a1, b3, acc[1][3], 0, 0, 0); \
    __builtin_amdgcn_sched_barrier(0);                                        \
    asm volatile("s_waitcnt vmcnt(1)");                                       \
    asm volatile("s_waitcnt lgkmcnt(0)");                                     \
    __builtin_amdgcn_s_barrier();                                             \
    __builtin_amdgcn_sched_barrier(0);                                        \
  } while (0)

  // Prologue
  K2_GLB(0, buf0);
  K2_LDX(0, st0);
  K2_LDX(1, st1);
  K2_LDX(2, st2);
  K2_AGEN(st0, buf0, 0);
  __builtin_amdgcn_sched_barrier(0);
  asm volatile("s_waitcnt vmcnt(2)");
  asm volatile("s_waitcnt lgkmcnt(0)");
  __builtin_amdgcn_s_barrier();
  __builtin_amdgcn_sched_barrier(0);

  for (int s4 = 0; s4 < 16; s4 += 4) {
    K2_ITER(s4 + 0, buf0, buf1, st1, st3);
    K2_ITER(s4 + 1, buf1, buf0, st2, st0);
    K2_ITER(s4 + 2, buf0, buf1, st3, st1);
    K2_ITER(s4 + 3, buf1, buf0, st0, st2);
  }
#undef K2_ITER
#undef K2_AGEN
#undef K2_LDX
#undef K2_GLB

  // Epilogue A: fragment image for this 32-j tile into buf0 B-area, copy out.
  int q = lane >> 4;
#pragma unroll
  for (int mi = 0; mi < 2; ++mi)
#pragma unroll
    for (int nn = 0; nn < 4; ++nn) {
      int u2 = wv * 4 + nn;
      int cell = (lane & 15) | ((((mi * 2) + (q >> 1)) & 3) << 4);
      uint2 v;
      v.x = f2bf(acc[mi][nn].x) | (f2bf(acc[mi][nn].y) << 16);
      v.y = f2bf(acc[mi][nn].z) | (f2bf(acc[mi][nn].w) << 16);
      *(uint2*)(buf0 + 2048 + u2 * 1024 + cell * 16 + ((q & 1) << 3)) = v;
    }
  __syncthreads();
  char* wb = WhTf + (size_t)blockIdx.x * 16384;
#pragma unroll
  for (int q2 = 0; q2 < 4; ++q2) {
    uint4 v = *(const uint4*)(buf0 + 2048 + q2 * 4096 + t * 16);
    *(uint4*)(wb + q2 * 4096 + t * 16) = v;
  }

  // Epilogue B: reduce Wh1/Wh2 over the 8 lanes sharing row jr, write, max.
  d1 += __shfl_xor(d1, 1);
  d1 += __shfl_xor(d1, 2);
  d1 += __shfl_xor(d1, 4);
  d2 += __shfl_xor(d2, 1);
  d2 += __shfl_xor(d2, 2);
  d2 += __shfl_xor(d2, 4);
  if ((t & 7) == 0) {
    Wh1[jb + jr] = d1;
    Wh2[jb + jr] = d2;
  }
  float mx = d2;
#pragma unroll
  for (int off = 32; off >= 8; off >>= 1) mx = fmaxf(mx, __shfl_xor(mx, off));
  __shared__ float red[4];
  if (lane == 0) red[wv] = mx;
  __syncthreads();
  if (t == 0) {
    float bm = fmaxf(fmaxf(red[0], red[1]), fmaxf(red[2], red[3]));
    atomicMax(maxkey, fkey(bm));
  }
}

// ---------------- k3: fused attention weights + PV matmul ----------------
__device__ __forceinline__ uint2 hv4(int4 aq, float4 wq, float wh1, float m,
                                     float enm, float& z) {
  float s0 = wh1 + wq.x, s1 = wh1 + wq.y, s2 = wh1 + wq.z, s3 = wh1 + wq.w;
  s0 = s0 > 0.f ? s0 : 0.2f * s0;
  s1 = s1 > 0.f ? s1 : 0.2f * s1;
  s2 = s2 > 0.f ? s2 : 0.2f * s2;
  s3 = s3 > 0.f ? s3 : 0.2f * s3;
  float w0 = aq.x > 0 ? __expf(s0 - m) : enm;
  float w1 = aq.y > 0 ? __expf(s1 - m) : enm;
  float w2 = aq.z > 0 ? __expf(s2 - m) : enm;
  float w3 = aq.w > 0 ? __expf(s3 - m) : enm;
  unsigned h0 = f2bf(w0), h1 = f2bf(w1), h2 = f2bf(w2), h3 = f2bf(w3);
  z += bf2f(h0) + bf2f(h1) + bf2f(h2) + bf2f(h3);
  uint2 r;
  r.x = h0 | (h1 << 16);
  r.y = h2 | (h3 << 16);
  return r;
}

__global__ __launch_bounds__(512, 4) void k3_attn(
    const int* __restrict__ adj, const char* __restrict__ WhTf,
    const float* __restrict__ Wh1, const float* __restrict__ Wh2,
    const unsigned* __restrict__ maxptr, float* __restrict__ PVp,
    float* __restrict__ Zp) {
  // buffer: [A: 4 units x 1KB][B: 2 tiles x 16KB] = 36864, double-buffered
  __shared__ char smem[2 * 36864];
  char* buf0 = smem;
  char* buf1 = smem + 36864;
  int t = threadIdx.x, wv = t >> 6, lane = t & 63;
  int kc = blockIdx.x & 1;
  int ib = blockIdx.x >> 1;  // 0..255
  int ibase = ib * IROWS;
  int jbch = kc * JCHUNK;
  int r0 = t >> 4;           // row in tile 0..31
  int jg = (t & 15) * 4;     // j offset 0..60
  int iglob = ibase + r0;
  float maxwh2 = fkey_dec(*maxptr);
  float wh1 = Wh1[iglob];
  float m = fmaxf(0.f, wh1 + maxwh2);
  float enm = __expf(-m);
  int cA = (r0 & 15) | (((jg >> 3) & 3) << 4);
  int swA = cA ^ (((cA >> 4) & 3) << 2);
  int aoff = ((r0 >> 4) * 2 + (jg >> 5)) * 1024 + swA * 16 + ((jg & 4) << 1);
  int slotR = lane ^ (((lane >> 4) & 3) << 2);
  const int* adjrow = adj + ((size_t)iglob << 13) + jbch + jg;
  const float* wh2p = Wh2 + jbch + jg;

  int4 st0_adj, st1_adj, st2_adj, st3_adj;
  float4 st0_wh2, st1_wh2, st2_wh2, st3_wh2;
  f32x4 acc[2][2];
#pragma unroll
  for (int a = 0; a < 2; ++a)
#pragma unroll
    for (int b = 0; b < 2; ++b) acc[a][b] = (f32x4){0.f, 0.f, 0.f, 0.f};
  float zacc = 0.f;

#define K3_GLB(SIDX, BUFW)                                                    \
  do {                                                                        \
    int jt_ = kc * 128 + (SIDX) * 2;                                          \
    const char* gs_ = WhTf + ((size_t)jt_ << 14) + (wv << 12) + lane * 16;    \
    char* ld_ = (BUFW) + 4096 + (wv << 12);                                   \
    GLDS(gs_, ld_);                                                           \
    GLDS(gs_ + 1024, ld_ + 1024);                                             \
    GLDS(gs_ + 2048, ld_ + 2048);                                             \
    GLDS(gs_ + 3072, ld_ + 3072);                                             \
  } while (0)

#define K3_LD(SIDX, ST)                                                       \
  do {                                                                        \
    ST##_adj = *(const int4*)(adjrow + (SIDX)*BKJ);                           \
    ST##_wh2 = *(const float4*)(wh2p + (SIDX)*BKJ);                           \
  } while (0)

#define K3_ITER(S, BUFR, BUFW, STC, STF)                                      \
  do {                                                                        \
    int s_ = (S);                                                             \
    if (s_ + 1 < NSTEP) K3_GLB(s_ + 1, BUFW);                                 \
    K3_LD((s_ + 3 < NSTEP) ? s_ + 3 : NSTEP - 1, STF);                        \
    if (s_ + 1 < NSTEP) {                                                     \
      uint2 a_ = hv4(STC##_adj, STC##_wh2, wh1, m, enm, zacc);                \
      *(uint2*)((BUFW) + aoff) = a_;                                          \
    }                                                                         \
    {                                                                         \
      const char* br_ = (BUFR);                                               \
      bf16x8 a0_ = *(const bf16x8*)(br_ + 0 * 1024 + slotR * 16);             \
      bf16x8 a1_ = *(const bf16x8*)(br_ + 2 * 1024 + slotR * 16);             \
      bf16x8 b0_ = *(const bf16x8*)(br_ + 4096 + (wv * 2 + 0) * 1024 + lane * 16); \
      bf16x8 b1_ = *(const bf16x8*)(br_ + 4096 + (wv * 2 + 1) * 1024 + lane * 16); \
      acc[0][0] = __builtin_amdgcn_mfma_f32_16x16x32_bf16(a0_, b0_, acc[0][0], 0, 0, 0); \
      acc[0][1] = __builtin_amdgcn_mfma_f32_16x16x32_bf16(a0_, b1_, acc[0][1], 0, 0, 0); \
      acc[1][0] = __builtin_amdgcn_mfma_f32_16x16x32_bf16(a1_, b0_, acc[1][0], 0, 0, 0); \
      acc[1][1] = __builtin_amdgcn_mfma_f32_16x16x32_bf16(a1_, b1_, acc[1][1], 0, 0, 0); \
      a0_ = *(const bf16x8*)(br_ + 1 * 1024 + slotR * 16);                    \
      a1_ = *(const bf16x8*)(br_ + 3 * 1024 + slotR * 16);                    \
      b0_ = *(const bf16x8*)(br_ + 4096 + 16384 + (wv * 2 + 0) * 1024 + lane * 16); \
      b1_ = *(const bf16x8*)(br_ + 4096 + 16384 + (wv * 2 + 1) * 1024 + lane * 16); \
      acc[0][0] = __builtin_amdgcn_mfma_f32_16x16x32_bf16(a0_, b0_, acc[0][0], 0, 0, 0); \
      acc[0][1] = __builtin_amdgcn_mfma_f32_16x16x32_bf16(a0_, b1_, acc[0][1], 0, 0, 0); \
      acc[1][0] = __builtin_amdgcn_mfma_f32_16x16x32_bf16(a1_, b0_, acc[1][0], 0, 0, 0); \
      acc[1][1] = __builtin_amdgcn_mfma_f32_16x16x32_bf16(a1_, b1_, acc[1][1], 0, 0, 0); \
    }                                                                         \
    __builtin_amdgcn_sched_barrier(0);                                        \
    asm volatile("s_waitcnt vmcnt(2)");                                       \
    asm volatile("s_waitcnt lgkmcnt(0)");                                     \
    __builtin_amdgcn_s_barrier();                                             \
    __builtin_amdgcn_sched_barrier(0);                                        \
  } while (0)

  // Prologue: GLDS(0)->buf0; adj 0,1,2 -> st0,st1,st2; A(0)->buf0.
  K3_GLB(0, buf0);
  K3_LD(0, st0);
  K3_LD(1, st1);
  K3_LD(2, st2);
  {
    uint2 a_ = hv4(st0_adj, st0_wh2, wh1, m, enm, zacc);
    *(uint2*)(buf0 + aoff) = a_;
  }
  __builtin_amdgcn_sched_barrier(0);
  asm volatile("s_waitcnt vmcnt(4)");
  asm volatile("s_waitcnt lgkmcnt(0)");
  __builtin_amdgcn_s_barrier();
  __builtin_amdgcn_sched_barrier(0);

  for (int s4 = 0; s4 < NSTEP; s4 += 4) {
    K3_ITER(s4 + 0, buf0, buf1, st1, st3);
    K3_ITER(s4 + 1, buf1, buf0, st2, st0);
    K3_ITER(s4 + 2, buf0, buf1, st3, st1);
    K3_ITER(s4 + 3, buf1, buf0, st0, st2);
  }
#undef K3_ITER
#undef K3_LD
#undef K3_GLB

  // Z reduce over the 16 threads sharing row r0.
  zacc += __shfl_xor(zacc, 1);
  zacc += __shfl_xor(zacc, 2);
  zacc += __shfl_xor(zacc, 4);
  zacc += __shfl_xor(zacc, 8);
  if ((t & 15) == 0) Zp[(size_t)kc * NR + iglob] = zacc;
#pragma unroll
  for (int rf = 0; rf < 2; ++rf)
#pragma unroll
    for (int un = 0; un < 2; ++un) {
      int f = wv * 32 + un * 16 + (lane & 15);
      int row0 = ibase + rf * 16 + ((lane >> 4) << 2);
      size_t base = ((size_t)kc * NR + row0) * FOUT + f;
      PVp[base + 0 * FOUT] = acc[rf][un].x;
      PVp[base + 1 * FOUT] = acc[rf][un].y;
      PVp[base + 2 * FOUT] = acc[rf][un].z;
      PVp[base + 3 * FOUT] = acc[rf][un].w;
    }
}

// ---------------- k4: reduce partials, normalize, relu ----------------
__global__ __launch_bounds__(256) void k4_reduce(const float* __restrict__ PVp,
                                                 const float* __restrict__ Zp,
                                                 float* __restrict__ out) {
  int tid = blockIdx.x * 256 + threadIdx.x;  // 0..524287
  int i = tid >> 6;
  int f4 = (tid & 63) * 4;
  float z = Zp[i] + Zp[NR + i];
  float4 p0 = *(const float4*)(PVp + (size_t)i * FOUT + f4);
  float4 p1 = *(const float4*)(PVp + ((size_t)NR + i) * FOUT + f4);
  float inv = 1.f / z;
  float4 r;
  r.x = fmaxf((p0.x + p1.x) * inv, 0.f);
  r.y = fmaxf((p0.y + p1.y) * inv, 0.f);
  r.z = fmaxf((p0.z + p1.z) * inv, 0.f);
  r.w = fmaxf((p0.w + p1.w) * inv, 0.f);
  *(float4*)(out + (size_t)i * FOUT + f4) = r;
}

// ---------------- launch ----------------
extern "C" void kernel_launch(void* const* d_in, const int* in_sizes, int n_in,
                              void* d_out, int out_size, void* d_ws,
                              size_t ws_size, hipStream_t stream) {
  const float* X = (const float*)d_in[0];
  const float* W = (const float*)d_in[1];
  const float* W2 = (const float*)d_in[2];
  const int* adj = (const int*)d_in[3];
  float* out = (float*)d_out;
  char* ws = (char*)d_ws;

  const size_t WHT_OFF = 0;                               // 4 MB fragment image
  const size_t WTBF_OFF = (size_t)4 * 1024 * 1024;        // 256 KB
  const size_t W1_OFF = WTBF_OFF + 256 * 1024;
  const size_t W2V_OFF = W1_OFF + 2048;
  const size_t WH1_OFF = W2V_OFF + 2048;
  const size_t WH2_OFF = WH1_OFF + 32768;
  const size_t MXK_OFF = WH2_OFF + 32768;
  const size_t ZP_OFF = MXK_OFF + 256;                    // float[2][8192]
  const size_t PV_OFF = ZP_OFF + (size_t)KSPLIT * NR * 4; // float[2][8192][256]

  char* WhTf = ws + WHT_OFF;
  char* WTbf = ws + WTBF_OFF;
  float* w1 = (float*)(ws + W1_OFF);
  float* w2 = (float*)(ws + W2V_OFF);
  float* Wh1 = (float*)(ws + WH1_OFF);
  float* Wh2 = (float*)(ws + WH2_OFF);
  unsigned* maxkey = (unsigned*)(ws + MXK_OFF);
  float* Zp = (float*)(ws + ZP_OFF);
  float* PVp = (float*)(ws + PV_OFF);

  k0_prep<<<128, 256, 0, stream>>>(W, W2, w1, w2, WTbf, maxkey);
  k2_fused<<<256, 256, 0, stream>>>(X, WTbf, w1, w2, WhTf, Wh1, Wh2, maxkey);
  k3_attn<<<512, 512, 0, stream>>>(adj, WhTf, Wh1, Wh2, maxkey, PVp, Zp);
  k4_reduce<<<2048, 256, 0, stream>>>(PVp, Zp, out);
}

// Round 5
// 130.427 us; speedup vs baseline: 2.6985x; 1.0685x over previous
//
#include <hip/hip_runtime.h>
#include <cstdint>
#include <cstddef>

// GraphAttentionLayer: N=8192, IN=512, OUT=256
//  k0: w1=W@W2[:256], w2=W@W2[256:], WTbf = bf16(W^T) fragment image, maxkey=0
//  k2f: WhTf = bf16(X@W)^T fragment image + Wh1/Wh2 (exact fp32) + max
//  k3: fused mask+lrelu+softmax-weights + (attention @ Wh). 512 thr, BKJ=64,
//      KSPLIT=2 -> 512 blocks = 2/CU. B-fragments global->REG (no LDS), A via
//      small dbuf LDS, barrier needs lgkm only (no vmcnt drain), adj prefetch
//      distance 4 (forced-complete at ~2 bodies > HBM latency).
//  k4: reduce 2 partials, divide by Z, relu
#define NR 8192
#define FOUT 256
#define KIN 512
#define KSPLIT 2
#define JCHUNK (NR / KSPLIT)  // 4096
#define BKJ 64
#define NSTEP (JCHUNK / BKJ)  // 64
#define IROWS 32

typedef __attribute__((ext_vector_type(8))) short bf16x8;
typedef __attribute__((ext_vector_type(4))) float f32x4;

__device__ __forceinline__ unsigned f2bf(float x) {
  unsigned u = __float_as_uint(x);
  u += 0x7fffu + ((u >> 16) & 1u);
  return u >> 16;
}
__device__ __forceinline__ float bf2f(unsigned h) {
  return __uint_as_float(h << 16);
}
// monotone float<->uint key for atomicMax (0 == -inf sentinel)
__device__ __forceinline__ unsigned fkey(float x) {
  unsigned u = __float_as_uint(x);
  return (u & 0x80000000u) ? ~u : (u | 0x80000000u);
}
__device__ __forceinline__ float fkey_dec(unsigned k) {
  return __uint_as_float((k & 0x80000000u) ? (k ^ 0x80000000u) : ~k);
}

#define GLDS(g, l)                                                            \
  __builtin_amdgcn_global_load_lds(                                           \
      (const __attribute__((address_space(1))) unsigned int*)(g),             \
      (__attribute__((address_space(3))) unsigned int*)(l), 16, 0, 0)

// ---------------- k0: w1, w2, WTbf (B-fragment image), maxkey init ---------
__global__ __launch_bounds__(256) void k0_prep(const float* __restrict__ W,
                                               const float* __restrict__ W2,
                                               float* __restrict__ w1,
                                               float* __restrict__ w2,
                                               char* __restrict__ WTbf,
                                               unsigned* __restrict__ maxkey) {
  if (blockIdx.x == 0 && threadIdx.x == 0) *maxkey = 0u;
  int wv = threadIdx.x >> 6, lane = threadIdx.x & 63;
  int k = blockIdx.x * 4 + wv;  // 0..511
  int f4 = lane * 4;
  float4 wr = *(const float4*)(W + (size_t)k * FOUT + f4);
  float4 a = *(const float4*)(W2 + f4);
  float4 b = *(const float4*)(W2 + FOUT + f4);
  float d1 = wr.x * a.x + wr.y * a.y + wr.z * a.z + wr.w * a.w;
  float d2 = wr.x * b.x + wr.y * b.y + wr.z * b.z + wr.w * b.w;
#pragma unroll
  for (int off = 32; off; off >>= 1) {
    d1 += __shfl_xor(d1, off);
    d2 += __shfl_xor(d2, off);
  }
  if (lane == 0) {
    w1[k] = d1;
    w2[k] = d2;
  }
  int kt = k >> 5, kl = k & 31;
  float wv4[4] = {wr.x, wr.y, wr.z, wr.w};
#pragma unroll
  for (int ff = 0; ff < 4; ++ff) {
    int f = f4 + ff;
    size_t addr = (size_t)kt * 16384 + (f >> 4) * 1024 +
                  (((f & 15) | (((kl >> 3) & 3) << 4)) * 16) + (kl & 7) * 2;
    *(unsigned short*)(WTbf + addr) = (unsigned short)f2bf(wv4[ff]);
  }
}

// ---------------- k2f: WhTf fragment image + Wh1/Wh2 + maxkey --------------
__global__ __launch_bounds__(256) void k2_fused(
    const float* __restrict__ X, const char* __restrict__ WTbf,
    const float* __restrict__ w1, const float* __restrict__ w2,
    char* __restrict__ WhTf, float* __restrict__ Wh1, float* __restrict__ Wh2,
    unsigned* __restrict__ maxkey) {
  // [dbuf: 2 x (A 2KB + B 16KB)][w-slices 4KB]
  __shared__ char smem[2 * 18432 + 4096];
  char* buf0 = smem;
  char* buf1 = smem + 18432;
  char* wlds = smem + 2 * 18432;  // w1 floats [0,2048), w2 floats [2048,4096)
  int t = threadIdx.x, wv = t >> 6, lane = t & 63;
  int jb = blockIdx.x * 32;
  int jr = t >> 3, koff = (t & 7) * 4;
  int cA = (jr & 15) | (((koff >> 3) & 3) << 4);
  int swA = cA ^ (((cA >> 4) & 3) << 2);
  int aoff = (jr >> 4) * 1024 + swA * 16 + ((koff & 4) << 1);
  int slotR = lane ^ (((lane >> 4) & 3) << 2);
  const float* xrow = X + (size_t)(jb + jr) * KIN + koff;

  // Stage w1/w2 into LDS (reads via lgkm, so they don't pollute vmcnt).
  {
    float2 a_ = *(const float2*)(w1 + t * 2);
    float2 b_ = *(const float2*)(w2 + t * 2);
    *(float2*)(wlds + t * 8) = a_;
    *(float2*)(wlds + 2048 + t * 8) = b_;
  }
  __syncthreads();

  float4 st0, st1, st2, st3;
  float d1 = 0.f, d2 = 0.f;
  f32x4 acc[2][4];
#pragma unroll
  for (int a = 0; a < 2; ++a)
#pragma unroll
    for (int b = 0; b < 4; ++b) acc[a][b] = (f32x4){0.f, 0.f, 0.f, 0.f};

#define K2_GLB(KT, BUFW)                                                      \
  do {                                                                        \
    const char* gs_ = WTbf + ((size_t)(KT) << 14) + (wv << 12) + lane * 16;   \
    char* ld_ = (BUFW) + 2048 + (wv << 12);                                   \
    GLDS(gs_, ld_);                                                           \
    GLDS(gs_ + 1024, ld_ + 1024);                                             \
    GLDS(gs_ + 2048, ld_ + 2048);                                             \
    GLDS(gs_ + 3072, ld_ + 3072);                                             \
  } while (0)

#define K2_LDX(KT, ST) (ST) = *(const float4*)(xrow + (KT) * 32)

#define K2_AGEN(ST, BUFW, SNUM)                                               \
  do {                                                                        \
    uint2 a_;                                                                 \
    a_.x = f2bf((ST).x) | (f2bf((ST).y) << 16);                               \
    a_.y = f2bf((ST).z) | (f2bf((ST).w) << 16);                               \
    *(uint2*)((BUFW) + aoff) = a_;                                            \
    float4 wa_ = *(const float4*)(wlds + ((SNUM)*32 + koff) * 4);             \
    float4 wb_ = *(const float4*)(wlds + 2048 + ((SNUM)*32 + koff) * 4);      \
    d1 += (ST).x * wa_.x + (ST).y * wa_.y + (ST).z * wa_.z + (ST).w * wa_.w;  \
    d2 += (ST).x * wb_.x + (ST).y * wb_.y + (ST).z * wb_.z + (ST).w * wb_.w;  \
  } while (0)

#define K2_ITER(S, BUFR, BUFW, STC, STF)                                      \
  do {                                                                        \
    int s_ = (S);                                                             \
    if (s_ + 1 < 16) K2_GLB(s_ + 1, BUFW);                                    \
    K2_LDX((s_ + 3 < 16) ? s_ + 3 : 15, STF);                                 \
    if (s_ + 1 < 16) K2_AGEN(STC, BUFW, s_ + 1);                              \
    bf16x8 a0 = *(const bf16x8*)((BUFR) + slotR * 16);                        \
    bf16x8 a1 = *(const bf16x8*)((BUFR) + 1024 + slotR * 16);                 \
    bf16x8 b0 = *(const bf16x8*)((BUFR) + 2048 + (wv * 4 + 0) * 1024 + lane * 16); \
    bf16x8 b1 = *(const bf16x8*)((BUFR) + 2048 + (wv * 4 + 1) * 1024 + lane * 16); \
    bf16x8 b2 = *(const bf16x8*)((BUFR) + 2048 + (wv * 4 + 2) * 1024 + lane * 16); \
    bf16x8 b3 = *(const bf16x8*)((BUFR) + 2048 + (wv * 4 + 3) * 1024 + lane * 16); \
    acc[0][0] = __builtin_amdgcn_mfma_f32_16x16x32_bf16(a0, b0, acc[0][0], 0, 0, 0); \
    acc[0][1] = __builtin_amdgcn_mfma_f32_16x16x32_bf16(a0, b1, acc[0][1], 0, 0, 0); \
    acc[0][2] = __builtin_amdgcn_mfma_f32_16x16x32_bf16(a0, b2, acc[0][2], 0, 0, 0); \
    acc[0][3] = __builtin_amdgcn_mfma_f32_16x16x32_bf16(a0, b3, acc[0][3], 0, 0, 0); \
    acc[1][0] = __builtin_amdgcn_mfma_f32_16x16x32_bf16(a1, b0, acc[1][0], 0, 0, 0); \
    acc[1][1] = __builtin_amdgcn_mfma_f32_16x16x32_bf16(a1, b1, acc[1][1], 0, 0, 0); \
    acc[1][2] = __builtin_amdgcn_mfma_f32_16x16x32_bf16(a1, b2, acc[1][2], 0, 0, 0); \
    acc[1][3] = __builtin_amdgcn_mfma_f32_16x16x32_bf16(a1, b3, acc[1][3], 0, 0, 0); \
    __builtin_amdgcn_sched_barrier(0);                                        \
    asm volatile("s_waitcnt vmcnt(1)");                                       \
    asm volatile("s_waitcnt lgkmcnt(0)");                                     \
    __builtin_amdgcn_s_barrier();                                             \
    __builtin_amdgcn_sched_barrier(0);                                        \
  } while (0)

  // Prologue
  K2_GLB(0, buf0);
  K2_LDX(0, st0);
  K2_LDX(1, st1);
  K2_LDX(2, st2);
  K2_AGEN(st0, buf0, 0);
  __builtin_amdgcn_sched_barrier(0);
  asm volatile("s_waitcnt vmcnt(2)");
  asm volatile("s_waitcnt lgkmcnt(0)");
  __builtin_amdgcn_s_barrier();
  __builtin_amdgcn_sched_barrier(0);

  for (int s4 = 0; s4 < 16; s4 += 4) {
    K2_ITER(s4 + 0, buf0, buf1, st1, st3);
    K2_ITER(s4 + 1, buf1, buf0, st2, st0);
    K2_ITER(s4 + 2, buf0, buf1, st3, st1);
    K2_ITER(s4 + 3, buf1, buf0, st0, st2);
  }
#undef K2_ITER
#undef K2_AGEN
#undef K2_LDX
#undef K2_GLB

  // Epilogue A: fragment image for this 32-j tile into buf0 B-area, copy out.
  int q = lane >> 4;
#pragma unroll
  for (int mi = 0; mi < 2; ++mi)
#pragma unroll
    for (int nn = 0; nn < 4; ++nn) {
      int u2 = wv * 4 + nn;
      int cell = (lane & 15) | ((((mi * 2) + (q >> 1)) & 3) << 4);
      uint2 v;
      v.x = f2bf(acc[mi][nn].x) | (f2bf(acc[mi][nn].y) << 16);
      v.y = f2bf(acc[mi][nn].z) | (f2bf(acc[mi][nn].w) << 16);
      *(uint2*)(buf0 + 2048 + u2 * 1024 + cell * 16 + ((q & 1) << 3)) = v;
    }
  __syncthreads();
  char* wb = WhTf + (size_t)blockIdx.x * 16384;
#pragma unroll
  for (int q2 = 0; q2 < 4; ++q2) {
    uint4 v = *(const uint4*)(buf0 + 2048 + q2 * 4096 + t * 16);
    *(uint4*)(wb + q2 * 4096 + t * 16) = v;
  }

  // Epilogue B: reduce Wh1/Wh2 over the 8 lanes sharing row jr, write, max.
  d1 += __shfl_xor(d1, 1);
  d1 += __shfl_xor(d1, 2);
  d1 += __shfl_xor(d1, 4);
  d2 += __shfl_xor(d2, 1);
  d2 += __shfl_xor(d2, 2);
  d2 += __shfl_xor(d2, 4);
  if ((t & 7) == 0) {
    Wh1[jb + jr] = d1;
    Wh2[jb + jr] = d2;
  }
  float mx = d2;
#pragma unroll
  for (int off = 32; off >= 8; off >>= 1) mx = fmaxf(mx, __shfl_xor(mx, off));
  __shared__ float red[4];
  if (lane == 0) red[wv] = mx;
  __syncthreads();
  if (t == 0) {
    float bm = fmaxf(fmaxf(red[0], red[1]), fmaxf(red[2], red[3]));
    atomicMax(maxkey, fkey(bm));
  }
}

// ---------------- k3: fused attention weights + PV matmul ----------------
__device__ __forceinline__ uint2 hv4(int4 aq, float4 wq, float wh1, float m,
                                     float enm, float& z) {
  float s0 = wh1 + wq.x, s1 = wh1 + wq.y, s2 = wh1 + wq.z, s3 = wh1 + wq.w;
  s0 = s0 > 0.f ? s0 : 0.2f * s0;
  s1 = s1 > 0.f ? s1 : 0.2f * s1;
  s2 = s2 > 0.f ? s2 : 0.2f * s2;
  s3 = s3 > 0.f ? s3 : 0.2f * s3;
  float w0 = aq.x > 0 ? __expf(s0 - m) : enm;
  float w1 = aq.y > 0 ? __expf(s1 - m) : enm;
  float w2 = aq.z > 0 ? __expf(s2 - m) : enm;
  float w3 = aq.w > 0 ? __expf(s3 - m) : enm;
  unsigned h0 = f2bf(w0), h1 = f2bf(w1), h2 = f2bf(w2), h3 = f2bf(w3);
  z += bf2f(h0) + bf2f(h1) + bf2f(h2) + bf2f(h3);
  uint2 r;
  r.x = h0 | (h1 << 16);
  r.y = h2 | (h3 << 16);
  return r;
}

__global__ __launch_bounds__(512, 4) void k3_attn(
    const int* __restrict__ adj, const char* __restrict__ WhTf,
    const float* __restrict__ Wh1, const float* __restrict__ Wh2,
    const unsigned* __restrict__ maxptr, float* __restrict__ PVp,
    float* __restrict__ Zp) {
  // [A dbuf 2 x 4KB][wh2 chunk 16KB] = 24576 B
  __shared__ char smem[24576];
  char* abuf0 = smem;
  char* abuf1 = smem + 4096;
  char* wlds = smem + 8192;
  int t = threadIdx.x, wv = t >> 6, lane = t & 63;
  int kc = blockIdx.x & 1;
  int ib = blockIdx.x >> 1;  // 0..255
  int ibase = ib * IROWS;
  int jbch = kc * JCHUNK;
  int r0 = t >> 4;           // row in tile 0..31
  int jg = (t & 15) * 4;     // j offset 0..60
  int iglob = ibase + r0;
  float maxwh2 = fkey_dec(*maxptr);
  float wh1 = Wh1[iglob];
  float m = fmaxf(0.f, wh1 + maxwh2);
  float enm = __expf(-m);
  int cA = (r0 & 15) | (((jg >> 3) & 3) << 4);
  int swA = cA ^ (((cA >> 4) & 3) << 2);
  int aoff = ((r0 >> 4) * 2 + (jg >> 5)) * 1024 + swA * 16 + ((jg & 4) << 1);
  int slotR = lane ^ (((lane >> 4) & 3) << 2);
  const int* adjrow = adj + ((size_t)iglob << 13) + jbch + jg;
  const char* bbase = WhTf + ((size_t)(kc * 128) << 14) + (size_t)(wv * 2) * 1024 +
                      (size_t)lane * 16;
  const char* wl = wlds + ((t & 15) << 4);

  // Stage this chunk's Wh2 (4096 floats = 16KB) into LDS once.
  {
    const float* wp = Wh2 + jbch + t * 8;
    *(float4*)(wlds + t * 32) = *(const float4*)(wp);
    *(float4*)(wlds + t * 32 + 16) = *(const float4*)(wp + 4);
  }
  __syncthreads();

  int4 st0, st1, st2, st3;
  bf16x8 bA0, bA1, bA2, bA3, bB0, bB1, bB2, bB3;
  f32x4 acc[2][2];
#pragma unroll
  for (int a = 0; a < 2; ++a)
#pragma unroll
    for (int b = 0; b < 2; ++b) acc[a][b] = (f32x4){0.f, 0.f, 0.f, 0.f};
  float zacc = 0.f;

  // B regs for step S: units (tile ks, un): b{0}=ks0un0 b{1}=ks0un1 b{2}=ks1un0 b{3}=ks1un1
#define K3_LDB(S, B0, B1, B2, B3)                                             \
  do {                                                                        \
    int sc_ = (S) < NSTEP ? (S) : NSTEP - 1;                                  \
    const char* bp_ = bbase + (size_t)(2 * sc_) * 16384;                      \
    B0 = *(const bf16x8*)(bp_);                                               \
    B1 = *(const bf16x8*)(bp_ + 1024);                                        \
    B2 = *(const bf16x8*)(bp_ + 16384);                                       \
    B3 = *(const bf16x8*)(bp_ + 16384 + 1024);                                \
  } while (0)

#define K3_LDA(S, ST)                                                         \
  do {                                                                        \
    int sc_ = (S) < NSTEP ? (S) : NSTEP - 1;                                  \
    ST = *(const int4*)(adjrow + sc_ * BKJ);                                  \
  } while (0)

  // Iter S: consume B(S) from {BC*}, A(S) from AR; fill B(S+1) into {BF*};
  // hv4 consumes STC (= adj(S+1)), writes A(S+1) to AW; refill STF <- adj(S+4).
#define K3_ITER(S, AR, AW, BC0, BC1, BC2, BC3, BF0, BF1, BF2, BF3, STC, STF,  \
                DO_HV)                                                        \
  do {                                                                        \
    int s_ = (S);                                                             \
    K3_LDB(s_ + 1, BF0, BF1, BF2, BF3);                                       \
    K3_LDA(s_ + 4, STF);                                                      \
    if (DO_HV) {                                                              \
      float4 wq_ = *(const float4*)(wl + (s_ + 1) * 256);                     \
      uint2 a_ = hv4(STC, wq_, wh1, m, enm, zacc);                            \
      *(uint2*)((AW) + aoff) = a_;                                            \
    }                                                                         \
    bf16x8 a00 = *(const bf16x8*)((AR) + 0 * 1024 + slotR * 16);              \
    bf16x8 a10 = *(const bf16x8*)((AR) + 2 * 1024 + slotR * 16);              \
    bf16x8 a01 = *(const bf16x8*)((AR) + 1 * 1024 + slotR * 16);              \
    bf16x8 a11 = *(const bf16x8*)((AR) + 3 * 1024 + slotR * 16);              \
    acc[0][0] = __builtin_amdgcn_mfma_f32_16x16x32_bf16(a00, BC0, acc[0][0], 0, 0, 0); \
    acc[0][1] = __builtin_amdgcn_mfma_f32_16x16x32_bf16(a00, BC1, acc[0][1], 0, 0, 0); \
    acc[1][0] = __builtin_amdgcn_mfma_f32_16x16x32_bf16(a10, BC0, acc[1][0], 0, 0, 0); \
    acc[1][1] = __builtin_amdgcn_mfma_f32_16x16x32_bf16(a10, BC1, acc[1][1], 0, 0, 0); \
    acc[0][0] = __builtin_amdgcn_mfma_f32_16x16x32_bf16(a01, BC2, acc[0][0], 0, 0, 0); \
    acc[0][1] = __builtin_amdgcn_mfma_f32_16x16x32_bf16(a01, BC3, acc[0][1], 0, 0, 0); \
    acc[1][0] = __builtin_amdgcn_mfma_f32_16x16x32_bf16(a11, BC2, acc[1][0], 0, 0, 0); \
    acc[1][1] = __builtin_amdgcn_mfma_f32_16x16x32_bf16(a11, BC3, acc[1][1], 0, 0, 0); \
    __builtin_amdgcn_sched_barrier(0);                                        \
    asm volatile("s_waitcnt lgkmcnt(0)" ::: "memory");                        \
    __builtin_amdgcn_s_barrier();                                             \
    __builtin_amdgcn_sched_barrier(0);                                        \
  } while (0)

  // Prologue: B(0)->bA; adj(0) immediate; adj(1,2,3)->st1,st2,st3; A(0)->abuf0.
  K3_LDB(0, bA0, bA1, bA2, bA3);
  int4 adj0;
  K3_LDA(0, adj0);
  K3_LDA(1, st1);
  K3_LDA(2, st2);
  K3_LDA(3, st3);
  {
    float4 wq0 = *(const float4*)(wl);
    uint2 a0 = hv4(adj0, wq0, wh1, m, enm, zacc);
    *(uint2*)(abuf0 + aoff) = a0;
  }
  __builtin_amdgcn_sched_barrier(0);
  asm volatile("s_waitcnt lgkmcnt(0)" ::: "memory");
  __builtin_amdgcn_s_barrier();
  __builtin_amdgcn_sched_barrier(0);

  // Steady: unroll 4 (A-buf/B-slot parity 2, adj slot rotation 4).
  for (int s4 = 0; s4 < NSTEP - 4; s4 += 4) {
    K3_ITER(s4 + 0, abuf0, abuf1, bA0, bA1, bA2, bA3, bB0, bB1, bB2, bB3, st1, st0, 1);
    K3_ITER(s4 + 1, abuf1, abuf0, bB0, bB1, bB2, bB3, bA0, bA1, bA2, bA3, st2, st1, 1);
    K3_ITER(s4 + 2, abuf0, abuf1, bA0, bA1, bA2, bA3, bB0, bB1, bB2, bB3, st3, st2, 1);
    K3_ITER(s4 + 3, abuf1, abuf0, bB0, bB1, bB2, bB3, bA0, bA1, bA2, bA3, st0, st3, 1);
  }
  // Final group: s = 60,61,62 with hv4 (steps 61..63), s = 63 without.
  K3_ITER(NSTEP - 4, abuf0, abuf1, bA0, bA1, bA2, bA3, bB0, bB1, bB2, bB3, st1, st0, 1);
  K3_ITER(NSTEP - 3, abuf1, abuf0, bB0, bB1, bB2, bB3, bA0, bA1, bA2, bA3, st2, st1, 1);
  K3_ITER(NSTEP - 2, abuf0, abuf1, bA0, bA1, bA2, bA3, bB0, bB1, bB2, bB3, st3, st2, 1);
  K3_ITER(NSTEP - 1, abuf1, abuf0, bB0, bB1, bB2, bB3, bA0, bA1, bA2, bA3, st0, st3, 0);
#undef K3_ITER
#undef K3_LDA
#undef K3_LDB

  // Z reduce over the 16 threads sharing row r0.
  zacc += __shfl_xor(zacc, 1);
  zacc += __shfl_xor(zacc, 2);
  zacc += __shfl_xor(zacc, 4);
  zacc += __shfl_xor(zacc, 8);
  if ((t & 15) == 0) Zp[(size_t)kc * NR + iglob] = zacc;
#pragma unroll
  for (int rf = 0; rf < 2; ++rf)
#pragma unroll
    for (int un = 0; un < 2; ++un) {
      int f = wv * 32 + un * 16 + (lane & 15);
      int row0 = ibase + rf * 16 + ((lane >> 4) << 2);
      size_t base = ((size_t)kc * NR + row0) * FOUT + f;
      PVp[base + 0 * FOUT] = acc[rf][un].x;
      PVp[base + 1 * FOUT] = acc[rf][un].y;
      PVp[base + 2 * FOUT] = acc[rf][un].z;
      PVp[base + 3 * FOUT] = acc[rf][un].w;
    }
}

// ---------------- k4: reduce partials, normalize, relu ----------------
__global__ __launch_bounds__(256) void k4_reduce(const float* __restrict__ PVp,
                                                 const float* __restrict__ Zp,
                                                 float* __restrict__ out) {
  int tid = blockIdx.x * 256 + threadIdx.x;  // 0..524287
  int i = tid >> 6;
  int f4 = (tid & 63) * 4;
  float z = Zp[i] + Zp[NR + i];
  float4 p0 = *(const float4*)(PVp + (size_t)i * FOUT + f4);
  float4 p1 = *(const float4*)(PVp + ((size_t)NR + i) * FOUT + f4);
  float inv = 1.f / z;
  float4 r;
  r.x = fmaxf((p0.x + p1.x) * inv, 0.f);
  r.y = fmaxf((p0.y + p1.y) * inv, 0.f);
  r.z = fmaxf((p0.z + p1.z) * inv, 0.f);
  r.w = fmaxf((p0.w + p1.w) * inv, 0.f);
  *(float4*)(out + (size_t)i * FOUT + f4) = r;
}

// ---------------- launch ----------------
extern "C" void kernel_launch(void* const* d_in, const int* in_sizes, int n_in,
                              void* d_out, int out_size, void* d_ws,
                              size_t ws_size, hipStream_t stream) {
  const float* X = (const float*)d_in[0];
  const float* W = (const float*)d_in[1];
  const float* W2 = (const float*)d_in[2];
  const int* adj = (const int*)d_in[3];
  float* out = (float*)d_out;
  char* ws = (char*)d_ws;

  const size_t WHT_OFF = 0;                               // 4 MB fragment image
  const size_t WTBF_OFF = (size_t)4 * 1024 * 1024;        // 256 KB
  const size_t W1_OFF = WTBF_OFF + 256 * 1024;
  const size_t W2V_OFF = W1_OFF + 2048;
  const size_t WH1_OFF = W2V_OFF + 2048;
  const size_t WH2_OFF = WH1_OFF + 32768;
  const size_t MXK_OFF = WH2_OFF + 32768;
  const size_t ZP_OFF = MXK_OFF + 256;                    // float[2][8192]
  const size_t PV_OFF = ZP_OFF + (size_t)KSPLIT * NR * 4; // float[2][8192][256]

  char* WhTf = ws + WHT_OFF;
  char* WTbf = ws + WTBF_OFF;
  float* w1 = (float*)(ws + W1_OFF);
  float* w2 = (float*)(ws + W2V_OFF);
  float* Wh1 = (float*)(ws + WH1_OFF);
  float* Wh2 = (float*)(ws + WH2_OFF);
  unsigned* maxkey = (unsigned*)(ws + MXK_OFF);
  float* Zp = (float*)(ws + ZP_OFF);
  float* PVp = (float*)(ws + PV_OFF);

  k0_prep<<<128, 256, 0, stream>>>(W, W2, w1, w2, WTbf, maxkey);
  k2_fused<<<256, 256, 0, stream>>>(X, WTbf, w1, w2, WhTf, Wh1, Wh2, maxkey);
  k3_attn<<<512, 512, 0, stream>>>(adj, WhTf, Wh1, Wh2, maxkey, PVp, Zp);
  k4_reduce<<<2048, 256, 0, stream>>>(PVp, Zp, out);
}

// Round 6
// 118.289 us; speedup vs baseline: 2.9754x; 1.1026x over previous
//
#include <hip/hip_runtime.h>
#include <cstdint>
#include <cstddef>

// GraphAttentionLayer: N=8192, IN=512, OUT=256
//  k0: w1=W@W2[:256], w2=W@W2[256:], WTbf = bf16(W^T) fragment image, maxkey=0
//  k2f: WhTf = bf16(X@W)^T fragment image + Wh1/Wh2 (exact fp32) + max
//  k3: fused mask+lrelu+softmax-weights + (attention @ Wh). IROWS=64, BKJ=64,
//      KSPLIT=4 -> 512 blocks x 512 thr = 2/CU. B global->REG (512MB L2/L3
//      total, halved vs r5), A via small dbuf LDS, lgkm-only barrier.
//  k4: reduce 4 partials, divide by Z, relu
#define NR 8192
#define FOUT 256
#define KIN 512
#define KSPLIT 4
#define JCHUNK (NR / KSPLIT)  // 2048
#define BKJ 64
#define NSTEP (JCHUNK / BKJ)  // 32
#define IROWS 64

typedef __attribute__((ext_vector_type(8))) short bf16x8;
typedef __attribute__((ext_vector_type(4))) float f32x4;

__device__ __forceinline__ unsigned f2bf(float x) {
  unsigned u = __float_as_uint(x);
  u += 0x7fffu + ((u >> 16) & 1u);
  return u >> 16;
}
__device__ __forceinline__ float bf2f(unsigned h) {
  return __uint_as_float(h << 16);
}
// monotone float<->uint key for atomicMax (0 == -inf sentinel)
__device__ __forceinline__ unsigned fkey(float x) {
  unsigned u = __float_as_uint(x);
  return (u & 0x80000000u) ? ~u : (u | 0x80000000u);
}
__device__ __forceinline__ float fkey_dec(unsigned k) {
  return __uint_as_float((k & 0x80000000u) ? (k ^ 0x80000000u) : ~k);
}

#define GLDS(g, l)                                                            \
  __builtin_amdgcn_global_load_lds(                                           \
      (const __attribute__((address_space(1))) unsigned int*)(g),             \
      (__attribute__((address_space(3))) unsigned int*)(l), 16, 0, 0)

// ---------------- k0: w1, w2, WTbf (B-fragment image), maxkey init ---------
__global__ __launch_bounds__(256) void k0_prep(const float* __restrict__ W,
                                               const float* __restrict__ W2,
                                               float* __restrict__ w1,
                                               float* __restrict__ w2,
                                               char* __restrict__ WTbf,
                                               unsigned* __restrict__ maxkey) {
  if (blockIdx.x == 0 && threadIdx.x == 0) *maxkey = 0u;
  int wv = threadIdx.x >> 6, lane = threadIdx.x & 63;
  int k = blockIdx.x * 4 + wv;  // 0..511
  int f4 = lane * 4;
  float4 wr = *(const float4*)(W + (size_t)k * FOUT + f4);
  float4 a = *(const float4*)(W2 + f4);
  float4 b = *(const float4*)(W2 + FOUT + f4);
  float d1 = wr.x * a.x + wr.y * a.y + wr.z * a.z + wr.w * a.w;
  float d2 = wr.x * b.x + wr.y * b.y + wr.z * b.z + wr.w * b.w;
#pragma unroll
  for (int off = 32; off; off >>= 1) {
    d1 += __shfl_xor(d1, off);
    d2 += __shfl_xor(d2, off);
  }
  if (lane == 0) {
    w1[k] = d1;
    w2[k] = d2;
  }
  int kt = k >> 5, kl = k & 31;
  float wv4[4] = {wr.x, wr.y, wr.z, wr.w};
#pragma unroll
  for (int ff = 0; ff < 4; ++ff) {
    int f = f4 + ff;
    size_t addr = (size_t)kt * 16384 + (f >> 4) * 1024 +
                  (((f & 15) | (((kl >> 3) & 3) << 4)) * 16) + (kl & 7) * 2;
    *(unsigned short*)(WTbf + addr) = (unsigned short)f2bf(wv4[ff]);
  }
}

// ---------------- k2f: WhTf fragment image + Wh1/Wh2 + maxkey --------------
__global__ __launch_bounds__(256) void k2_fused(
    const float* __restrict__ X, const char* __restrict__ WTbf,
    const float* __restrict__ w1, const float* __restrict__ w2,
    char* __restrict__ WhTf, float* __restrict__ Wh1, float* __restrict__ Wh2,
    unsigned* __restrict__ maxkey) {
  // [dbuf: 2 x (A 2KB + B 16KB)][w-slices 4KB]
  __shared__ char smem[2 * 18432 + 4096];
  char* buf0 = smem;
  char* buf1 = smem + 18432;
  char* wlds = smem + 2 * 18432;  // w1 floats [0,2048), w2 floats [2048,4096)
  int t = threadIdx.x, wv = t >> 6, lane = t & 63;
  int jb = blockIdx.x * 32;
  int jr = t >> 3, koff = (t & 7) * 4;
  int cA = (jr & 15) | (((koff >> 3) & 3) << 4);
  int swA = cA ^ (((cA >> 4) & 3) << 2);
  int aoff = (jr >> 4) * 1024 + swA * 16 + ((koff & 4) << 1);
  int slotR = lane ^ (((lane >> 4) & 3) << 2);
  const float* xrow = X + (size_t)(jb + jr) * KIN + koff;

  // Stage w1/w2 into LDS (reads via lgkm, so they don't pollute vmcnt).
  {
    float2 a_ = *(const float2*)(w1 + t * 2);
    float2 b_ = *(const float2*)(w2 + t * 2);
    *(float2*)(wlds + t * 8) = a_;
    *(float2*)(wlds + 2048 + t * 8) = b_;
  }
  __syncthreads();

  float4 st0, st1, st2, st3;
  float d1 = 0.f, d2 = 0.f;
  f32x4 acc[2][4];
#pragma unroll
  for (int a = 0; a < 2; ++a)
#pragma unroll
    for (int b = 0; b < 4; ++b) acc[a][b] = (f32x4){0.f, 0.f, 0.f, 0.f};

#define K2_GLB(KT, BUFW)                                                      \
  do {                                                                        \
    const char* gs_ = WTbf + ((size_t)(KT) << 14) + (wv << 12) + lane * 16;   \
    char* ld_ = (BUFW) + 2048 + (wv << 12);                                   \
    GLDS(gs_, ld_);                                                           \
    GLDS(gs_ + 1024, ld_ + 1024);                                             \
    GLDS(gs_ + 2048, ld_ + 2048);                                             \
    GLDS(gs_ + 3072, ld_ + 3072);                                             \
  } while (0)

#define K2_LDX(KT, ST) (ST) = *(const float4*)(xrow + (KT) * 32)

#define K2_AGEN(ST, BUFW, SNUM)                                               \
  do {                                                                        \
    uint2 a_;                                                                 \
    a_.x = f2bf((ST).x) | (f2bf((ST).y) << 16);                               \
    a_.y = f2bf((ST).z) | (f2bf((ST).w) << 16);                               \
    *(uint2*)((BUFW) + aoff) = a_;                                            \
    float4 wa_ = *(const float4*)(wlds + ((SNUM)*32 + koff) * 4);             \
    float4 wb_ = *(const float4*)(wlds + 2048 + ((SNUM)*32 + koff) * 4);      \
    d1 += (ST).x * wa_.x + (ST).y * wa_.y + (ST).z * wa_.z + (ST).w * wa_.w;  \
    d2 += (ST).x * wb_.x + (ST).y * wb_.y + (ST).z * wb_.z + (ST).w * wb_.w;  \
  } while (0)

#define K2_ITER(S, BUFR, BUFW, STC, STF)                                      \
  do {                                                                        \
    int s_ = (S);                                                             \
    if (s_ + 1 < 16) K2_GLB(s_ + 1, BUFW);                                    \
    K2_LDX((s_ + 3 < 16) ? s_ + 3 : 15, STF);                                 \
    if (s_ + 1 < 16) K2_AGEN(STC, BUFW, s_ + 1);                              \
    bf16x8 a0 = *(const bf16x8*)((BUFR) + slotR * 16);                        \
    bf16x8 a1 = *(const bf16x8*)((BUFR) + 1024 + slotR * 16);                 \
    bf16x8 b0 = *(const bf16x8*)((BUFR) + 2048 + (wv * 4 + 0) * 1024 + lane * 16); \
    bf16x8 b1 = *(const bf16x8*)((BUFR) + 2048 + (wv * 4 + 1) * 1024 + lane * 16); \
    bf16x8 b2 = *(const bf16x8*)((BUFR) + 2048 + (wv * 4 + 2) * 1024 + lane * 16); \
    bf16x8 b3 = *(const bf16x8*)((BUFR) + 2048 + (wv * 4 + 3) * 1024 + lane * 16); \
    acc[0][0] = __builtin_amdgcn_mfma_f32_16x16x32_bf16(a0, b0, acc[0][0], 0, 0, 0); \
    acc[0][1] = __builtin_amdgcn_mfma_f32_16x16x32_bf16(a0, b1, acc[0][1], 0, 0, 0); \
    acc[0][2] = __builtin_amdgcn_mfma_f32_16x16x32_bf16(a0, b2, acc[0][2], 0, 0, 0); \
    acc[0][3] = __builtin_amdgcn_mfma_f32_16x16x32_bf16(a0, b3, acc[0][3], 0, 0, 0); \
    acc[1][0] = __builtin_amdgcn_mfma_f32_16x16x32_bf16(a1, b0, acc[1][0], 0, 0, 0); \
    acc[1][1] = __builtin_amdgcn_mfma_f32_16x16x32_bf16(a1, b1, acc[1][1], 0, 0, 0); \
    acc[1][2] = __builtin_amdgcn_mfma_f32_16x16x32_bf16(a1, b2, acc[1][2], 0, 0, 0); \
    acc[1][3] = __builtin_amdgcn_mfma_f32_16x16x32_bf16(a1, b3, acc[1][3], 0, 0, 0); \
    __builtin_amdgcn_sched_barrier(0);                                        \
    asm volatile("s_waitcnt vmcnt(1)");                                       \
    asm volatile("s_waitcnt lgkmcnt(0)");                                     \
    __builtin_amdgcn_s_barrier();                                             \
    __builtin_amdgcn_sched_barrier(0);                                        \
  } while (0)

  // Prologue
  K2_GLB(0, buf0);
  K2_LDX(0, st0);
  K2_LDX(1, st1);
  K2_LDX(2, st2);
  K2_AGEN(st0, buf0, 0);
  __builtin_amdgcn_sched_barrier(0);
  asm volatile("s_waitcnt vmcnt(2)");
  asm volatile("s_waitcnt lgkmcnt(0)");
  __builtin_amdgcn_s_barrier();
  __builtin_amdgcn_sched_barrier(0);

  for (int s4 = 0; s4 < 16; s4 += 4) {
    K2_ITER(s4 + 0, buf0, buf1, st1, st3);
    K2_ITER(s4 + 1, buf1, buf0, st2, st0);
    K2_ITER(s4 + 2, buf0, buf1, st3, st1);
    K2_ITER(s4 + 3, buf1, buf0, st0, st2);
  }
#undef K2_ITER
#undef K2_AGEN
#undef K2_LDX
#undef K2_GLB

  // Epilogue A: fragment image for this 32-j tile into buf0 B-area, copy out.
  int q = lane >> 4;
#pragma unroll
  for (int mi = 0; mi < 2; ++mi)
#pragma unroll
    for (int nn = 0; nn < 4; ++nn) {
      int u2 = wv * 4 + nn;
      int cell = (lane & 15) | ((((mi * 2) + (q >> 1)) & 3) << 4);
      uint2 v;
      v.x = f2bf(acc[mi][nn].x) | (f2bf(acc[mi][nn].y) << 16);
      v.y = f2bf(acc[mi][nn].z) | (f2bf(acc[mi][nn].w) << 16);
      *(uint2*)(buf0 + 2048 + u2 * 1024 + cell * 16 + ((q & 1) << 3)) = v;
    }
  __syncthreads();
  char* wb = WhTf + (size_t)blockIdx.x * 16384;
#pragma unroll
  for (int q2 = 0; q2 < 4; ++q2) {
    uint4 v = *(const uint4*)(buf0 + 2048 + q2 * 4096 + t * 16);
    *(uint4*)(wb + q2 * 4096 + t * 16) = v;
  }

  // Epilogue B: reduce Wh1/Wh2 over the 8 lanes sharing row jr, write, max.
  d1 += __shfl_xor(d1, 1);
  d1 += __shfl_xor(d1, 2);
  d1 += __shfl_xor(d1, 4);
  d2 += __shfl_xor(d2, 1);
  d2 += __shfl_xor(d2, 2);
  d2 += __shfl_xor(d2, 4);
  if ((t & 7) == 0) {
    Wh1[jb + jr] = d1;
    Wh2[jb + jr] = d2;
  }
  float mx = d2;
#pragma unroll
  for (int off = 32; off >= 8; off >>= 1) mx = fmaxf(mx, __shfl_xor(mx, off));
  __shared__ float red[4];
  if (lane == 0) red[wv] = mx;
  __syncthreads();
  if (t == 0) {
    float bm = fmaxf(fmaxf(red[0], red[1]), fmaxf(red[2], red[3]));
    atomicMax(maxkey, fkey(bm));
  }
}

// ---------------- k3: fused attention weights + PV matmul ----------------
__device__ __forceinline__ uint2 hv4(int4 aq, float4 wq, float wh1, float m,
                                     float enm, float& z) {
  float s0 = wh1 + wq.x, s1 = wh1 + wq.y, s2 = wh1 + wq.z, s3 = wh1 + wq.w;
  s0 = s0 > 0.f ? s0 : 0.2f * s0;
  s1 = s1 > 0.f ? s1 : 0.2f * s1;
  s2 = s2 > 0.f ? s2 : 0.2f * s2;
  s3 = s3 > 0.f ? s3 : 0.2f * s3;
  float w0 = aq.x > 0 ? __expf(s0 - m) : enm;
  float w1 = aq.y > 0 ? __expf(s1 - m) : enm;
  float w2 = aq.z > 0 ? __expf(s2 - m) : enm;
  float w3 = aq.w > 0 ? __expf(s3 - m) : enm;
  unsigned h0 = f2bf(w0), h1 = f2bf(w1), h2 = f2bf(w2), h3 = f2bf(w3);
  z += bf2f(h0) + bf2f(h1) + bf2f(h2) + bf2f(h3);
  uint2 r;
  r.x = h0 | (h1 << 16);
  r.y = h2 | (h3 << 16);
  return r;
}
__device__ __forceinline__ uint4 hv8(int4 a0, int4 a1, float4 w0, float4 w1,
                                     float wh1, float m, float enm, float& z) {
  uint2 r0 = hv4(a0, w0, wh1, m, enm, z);
  uint2 r1 = hv4(a1, w1, wh1, m, enm, z);
  return (uint4){r0.x, r0.y, r1.x, r1.y};
}

__global__ __launch_bounds__(512, 4) void k3_attn(
    const int* __restrict__ adj, const char* __restrict__ WhTf,
    const float* __restrict__ Wh1, const float* __restrict__ Wh2,
    const unsigned* __restrict__ maxptr, float* __restrict__ PVp,
    float* __restrict__ Zp) {
  // [A dbuf 2 x 8KB][wh2 chunk 8KB] = 24576 B
  __shared__ char smem[24576];
  char* abuf0 = smem;
  char* abuf1 = smem + 8192;
  char* wlds = smem + 16384;
  int t = threadIdx.x, wv = t >> 6, lane = t & 63;
  int kc = blockIdx.x & 3;
  int ib = blockIdx.x >> 2;  // 0..127
  int ibase = ib * IROWS;
  int jbch = kc * JCHUNK;
  int r0 = t >> 3;           // row in tile 0..63
  int j8 = (t & 7) * 8;      // j offset 0..56
  int iglob = ibase + r0;
  float maxwh2 = fkey_dec(*maxptr);
  float wh1 = Wh1[iglob];
  float m = fmaxf(0.f, wh1 + maxwh2);
  float enm = __expf(-m);
  // A-image: unit = (r0>>4)*2 + ks (ks = j8>>5); cell = (r0&15)|(slot<<4),
  // slot = (j8&31)>>3; thread writes one full 16B cell (8 bf16 = its 8 j's).
  int unitA = (r0 >> 4) * 2 + (j8 >> 5);
  int cA = (r0 & 15) | (((j8 & 31) >> 3) << 4);
  int swA = cA ^ (((cA >> 4) & 3) << 2);
  int aoff = unitA * 1024 + swA * 16;
  int slotR = lane ^ (((lane >> 4) & 3) << 2);
  const int* adjrow = adj + ((size_t)iglob << 13) + jbch + j8;
  const char* bbase = WhTf + ((size_t)(kc * 64) << 14) +
                      (size_t)(wv * 2) * 1024 + (size_t)lane * 16;
  const char* wl = wlds + j8 * 4;

  // Stage this chunk's Wh2 (2048 floats = 8KB) into LDS once.
  *(float4*)(wlds + t * 16) = *(const float4*)(Wh2 + jbch + t * 4);
  __syncthreads();

  bf16x8 bA0, bA1, bA2, bA3, bB0, bB1, bB2, bB3;
  int4 st0_a, st0_b, st1_a, st1_b;
  f32x4 acc[4][2];
#pragma unroll
  for (int a = 0; a < 4; ++a)
#pragma unroll
    for (int b = 0; b < 2; ++b) acc[a][b] = (f32x4){0.f, 0.f, 0.f, 0.f};
  float zacc = 0.f;

#define K3_LDB(S, B0, B1, B2, B3)                                             \
  do {                                                                        \
    int sc_ = (S) < NSTEP ? (S) : NSTEP - 1;                                  \
    const char* bp_ = bbase + (size_t)(2 * sc_) * 16384;                      \
    B0 = *(const bf16x8*)(bp_);                                               \
    B1 = *(const bf16x8*)(bp_ + 1024);                                        \
    B2 = *(const bf16x8*)(bp_ + 16384);                                       \
    B3 = *(const bf16x8*)(bp_ + 16384 + 1024);                                \
  } while (0)

#define K3_LDA(S, ST)                                                         \
  do {                                                                        \
    int sc_ = (S) < NSTEP ? (S) : NSTEP - 1;                                  \
    ST##_a = *(const int4*)(adjrow + sc_ * BKJ);                              \
    ST##_b = *(const int4*)(adjrow + sc_ * BKJ + 4);                          \
  } while (0)

  // Iter S: B(S+1)->BF; hv consumes STC (= adj(S+1)), writes A(S+1) to AW;
  // refill STC <- adj(S+3); MFMA consumes A(S) from AR and B(S) from BC.
#define K3_ITER(S, AR, AW, BC0, BC1, BC2, BC3, BF0, BF1, BF2, BF3, STC, DO_HV) \
  do {                                                                        \
    int s_ = (S);                                                             \
    K3_LDB(s_ + 1, BF0, BF1, BF2, BF3);                                       \
    if (DO_HV) {                                                              \
      float4 wq0_ = *(const float4*)(wl + (s_ + 1) * 256);                    \
      float4 wq1_ = *(const float4*)(wl + (s_ + 1) * 256 + 16);               \
      uint4 a_ = hv8(STC##_a, STC##_b, wq0_, wq1_, wh1, m, enm, zacc);        \
      *(uint4*)((AW) + aoff) = a_;                                            \
    }                                                                         \
    K3_LDA(s_ + 3, STC);                                                      \
    _Pragma("unroll")                                                         \
    for (int rf_ = 0; rf_ < 4; ++rf_) {                                       \
      bf16x8 ak0_ = *(const bf16x8*)((AR) + (rf_ * 2 + 0) * 1024 + slotR * 16); \
      bf16x8 ak1_ = *(const bf16x8*)((AR) + (rf_ * 2 + 1) * 1024 + slotR * 16); \
      acc[rf_][0] = __builtin_amdgcn_mfma_f32_16x16x32_bf16(ak0_, BC0, acc[rf_][0], 0, 0, 0); \
      acc[rf_][1] = __builtin_amdgcn_mfma_f32_16x16x32_bf16(ak0_, BC1, acc[rf_][1], 0, 0, 0); \
      acc[rf_][0] = __builtin_amdgcn_mfma_f32_16x16x32_bf16(ak1_, BC2, acc[rf_][0], 0, 0, 0); \
      acc[rf_][1] = __builtin_amdgcn_mfma_f32_16x16x32_bf16(ak1_, BC3, acc[rf_][1], 0, 0, 0); \
    }                                                                         \
    __builtin_amdgcn_sched_barrier(0);                                        \
    asm volatile("s_waitcnt lgkmcnt(0)" ::: "memory");                        \
    __builtin_amdgcn_s_barrier();                                             \
    __builtin_amdgcn_sched_barrier(0);                                        \
  } while (0)

  // Prologue: B(0)->bA; adj(0) immediate; adj(1)->st1, adj(2)->st0; A(0)->abuf0.
  K3_LDB(0, bA0, bA1, bA2, bA3);
  int4 adj0a = *(const int4*)(adjrow);
  int4 adj0b = *(const int4*)(adjrow + 4);
  K3_LDA(1, st1);
  K3_LDA(2, st0);
  {
    float4 wq0 = *(const float4*)(wl);
    float4 wq1 = *(const float4*)(wl + 16);
    uint4 a0 = hv8(adj0a, adj0b, wq0, wq1, wh1, m, enm, zacc);
    *(uint4*)(abuf0 + aoff) = a0;
  }
  __builtin_amdgcn_sched_barrier(0);
  asm volatile("s_waitcnt lgkmcnt(0)" ::: "memory");
  __builtin_amdgcn_s_barrier();
  __builtin_amdgcn_sched_barrier(0);

  for (int s2 = 0; s2 < NSTEP - 2; s2 += 2) {
    K3_ITER(s2 + 0, abuf0, abuf1, bA0, bA1, bA2, bA3, bB0, bB1, bB2, bB3, st1, 1);
    K3_ITER(s2 + 1, abuf1, abuf0, bB0, bB1, bB2, bB3, bA0, bA1, bA2, bA3, st0, 1);
  }
  K3_ITER(NSTEP - 2, abuf0, abuf1, bA0, bA1, bA2, bA3, bB0, bB1, bB2, bB3, st1, 1);
  K3_ITER(NSTEP - 1, abuf1, abuf0, bB0, bB1, bB2, bB3, bA0, bA1, bA2, bA3, st0, 0);
#undef K3_ITER
#undef K3_LDA
#undef K3_LDB

  // Z reduce over the 8 threads sharing row r0.
  zacc += __shfl_xor(zacc, 1);
  zacc += __shfl_xor(zacc, 2);
  zacc += __shfl_xor(zacc, 4);
  if ((t & 7) == 0) Zp[(size_t)kc * NR + iglob] = zacc;
#pragma unroll
  for (int rf = 0; rf < 4; ++rf)
#pragma unroll
    for (int un = 0; un < 2; ++un) {
      int f = (wv * 2 + un) * 16 + (lane & 15);
      int row0 = ibase + rf * 16 + ((lane >> 4) << 2);
      size_t base = ((size_t)kc * NR + row0) * FOUT + f;
      PVp[base + 0 * FOUT] = acc[rf][un].x;
      PVp[base + 1 * FOUT] = acc[rf][un].y;
      PVp[base + 2 * FOUT] = acc[rf][un].z;
      PVp[base + 3 * FOUT] = acc[rf][un].w;
    }
}

// ---------------- k4: reduce partials, normalize, relu ----------------
__global__ __launch_bounds__(256) void k4_reduce(const float* __restrict__ PVp,
                                                 const float* __restrict__ Zp,
                                                 float* __restrict__ out) {
  int tid = blockIdx.x * 256 + threadIdx.x;  // 0..524287
  int i = tid >> 6;
  int f4 = (tid & 63) * 4;
  float z = Zp[i] + Zp[NR + i] + Zp[2 * NR + i] + Zp[3 * NR + i];
  float4 a = {0.f, 0.f, 0.f, 0.f};
#pragma unroll
  for (int c = 0; c < KSPLIT; ++c) {
    float4 p = *(const float4*)(PVp + ((size_t)c * NR + i) * FOUT + f4);
    a.x += p.x;
    a.y += p.y;
    a.z += p.z;
    a.w += p.w;
  }
  float inv = 1.f / z;
  float4 r;
  r.x = fmaxf(a.x * inv, 0.f);
  r.y = fmaxf(a.y * inv, 0.f);
  r.z = fmaxf(a.z * inv, 0.f);
  r.w = fmaxf(a.w * inv, 0.f);
  *(float4*)(out + (size_t)i * FOUT + f4) = r;
}

// ---------------- launch ----------------
extern "C" void kernel_launch(void* const* d_in, const int* in_sizes, int n_in,
                              void* d_out, int out_size, void* d_ws,
                              size_t ws_size, hipStream_t stream) {
  const float* X = (const float*)d_in[0];
  const float* W = (const float*)d_in[1];
  const float* W2 = (const float*)d_in[2];
  const int* adj = (const int*)d_in[3];
  float* out = (float*)d_out;
  char* ws = (char*)d_ws;

  const size_t WHT_OFF = 0;                               // 4 MB fragment image
  const size_t WTBF_OFF = (size_t)4 * 1024 * 1024;        // 256 KB
  const size_t W1_OFF = WTBF_OFF + 256 * 1024;
  const size_t W2V_OFF = W1_OFF + 2048;
  const size_t WH1_OFF = W2V_OFF + 2048;
  const size_t WH2_OFF = WH1_OFF + 32768;
  const size_t MXK_OFF = WH2_OFF + 32768;
  const size_t ZP_OFF = MXK_OFF + 256;                    // float[4][8192]
  const size_t PV_OFF = ZP_OFF + (size_t)KSPLIT * NR * 4; // float[4][8192][256]

  char* WhTf = ws + WHT_OFF;
  char* WTbf = ws + WTBF_OFF;
  float* w1 = (float*)(ws + W1_OFF);
  float* w2 = (float*)(ws + W2V_OFF);
  float* Wh1 = (float*)(ws + WH1_OFF);
  float* Wh2 = (float*)(ws + WH2_OFF);
  unsigned* maxkey = (unsigned*)(ws + MXK_OFF);
  float* Zp = (float*)(ws + ZP_OFF);
  float* PVp = (float*)(ws + PV_OFF);

  k0_prep<<<128, 256, 0, stream>>>(W, W2, w1, w2, WTbf, maxkey);
  k2_fused<<<256, 256, 0, stream>>>(X, WTbf, w1, w2, WhTf, Wh1, Wh2, maxkey);
  k3_attn<<<512, 512, 0, stream>>>(adj, WhTf, Wh1, Wh2, maxkey, PVp, Zp);
  k4_reduce<<<2048, 256, 0, stream>>>(PVp, Zp, out);
}

// Round 7
// 113.042 us; speedup vs baseline: 3.1135x; 1.0464x over previous
//
#include <hip/hip_runtime.h>
#include <cstdint>
#include <cstddef>

// GraphAttentionLayer: N=8192, IN=512, OUT=256
//  k0: w1=W@W2[:256], w2=W@W2[256:], WTbf = bf16(W^T) fragment image, maxkey=0
//  k2f: WhTf = bf16(X@W)^T fragment image + Wh1/Wh2 (exact fp32) + max
//  k3: fused mask+lrelu+softmax-weights + (attention @ Wh). IROWS=128, BKJ=64,
//      KSPLIT=4 -> 256 blocks x 1024 thr = 1/CU (16 waves). B global->REG
//      (256MB total, L2-resident per XCD), A via dbuf LDS, lgkm-only barrier.
//  k4: reduce 4 partials, divide by Z, relu
#define NR 8192
#define FOUT 256
#define KIN 512
#define KSPLIT 4
#define JCHUNK (NR / KSPLIT)  // 2048
#define BKJ 64
#define NSTEP (JCHUNK / BKJ)  // 32
#define IROWS 128

typedef __attribute__((ext_vector_type(8))) short bf16x8;
typedef __attribute__((ext_vector_type(4))) float f32x4;

__device__ __forceinline__ unsigned f2bf(float x) {
  unsigned u = __float_as_uint(x);
  u += 0x7fffu + ((u >> 16) & 1u);
  return u >> 16;
}
__device__ __forceinline__ float bf2f(unsigned h) {
  return __uint_as_float(h << 16);
}
// monotone float<->uint key for atomicMax (0 == -inf sentinel)
__device__ __forceinline__ unsigned fkey(float x) {
  unsigned u = __float_as_uint(x);
  return (u & 0x80000000u) ? ~u : (u | 0x80000000u);
}
__device__ __forceinline__ float fkey_dec(unsigned k) {
  return __uint_as_float((k & 0x80000000u) ? (k ^ 0x80000000u) : ~k);
}

#define GLDS(g, l)                                                            \
  __builtin_amdgcn_global_load_lds(                                           \
      (const __attribute__((address_space(1))) unsigned int*)(g),             \
      (__attribute__((address_space(3))) unsigned int*)(l), 16, 0, 0)

// ---------------- k0: w1, w2, WTbf (B-fragment image), maxkey init ---------
__global__ __launch_bounds__(256) void k0_prep(const float* __restrict__ W,
                                               const float* __restrict__ W2,
                                               float* __restrict__ w1,
                                               float* __restrict__ w2,
                                               char* __restrict__ WTbf,
                                               unsigned* __restrict__ maxkey) {
  if (blockIdx.x == 0 && threadIdx.x == 0) *maxkey = 0u;
  int wv = threadIdx.x >> 6, lane = threadIdx.x & 63;
  int k = blockIdx.x * 4 + wv;  // 0..511
  int f4 = lane * 4;
  float4 wr = *(const float4*)(W + (size_t)k * FOUT + f4);
  float4 a = *(const float4*)(W2 + f4);
  float4 b = *(const float4*)(W2 + FOUT + f4);
  float d1 = wr.x * a.x + wr.y * a.y + wr.z * a.z + wr.w * a.w;
  float d2 = wr.x * b.x + wr.y * b.y + wr.z * b.z + wr.w * b.w;
#pragma unroll
  for (int off = 32; off; off >>= 1) {
    d1 += __shfl_xor(d1, off);
    d2 += __shfl_xor(d2, off);
  }
  if (lane == 0) {
    w1[k] = d1;
    w2[k] = d2;
  }
  int kt = k >> 5, kl = k & 31;
  float wv4[4] = {wr.x, wr.y, wr.z, wr.w};
#pragma unroll
  for (int ff = 0; ff < 4; ++ff) {
    int f = f4 + ff;
    size_t addr = (size_t)kt * 16384 + (f >> 4) * 1024 +
                  (((f & 15) | (((kl >> 3) & 3) << 4)) * 16) + (kl & 7) * 2;
    *(unsigned short*)(WTbf + addr) = (unsigned short)f2bf(wv4[ff]);
  }
}

// ---------------- k2f: WhTf fragment image + Wh1/Wh2 + maxkey --------------
__global__ __launch_bounds__(256) void k2_fused(
    const float* __restrict__ X, const char* __restrict__ WTbf,
    const float* __restrict__ w1, const float* __restrict__ w2,
    char* __restrict__ WhTf, float* __restrict__ Wh1, float* __restrict__ Wh2,
    unsigned* __restrict__ maxkey) {
  // [dbuf: 2 x (A 2KB + B 16KB)][w-slices 4KB]
  __shared__ char smem[2 * 18432 + 4096];
  char* buf0 = smem;
  char* buf1 = smem + 18432;
  char* wlds = smem + 2 * 18432;  // w1 floats [0,2048), w2 floats [2048,4096)
  int t = threadIdx.x, wv = t >> 6, lane = t & 63;
  int jb = blockIdx.x * 32;
  int jr = t >> 3, koff = (t & 7) * 4;
  int cA = (jr & 15) | (((koff >> 3) & 3) << 4);
  int swA = cA ^ (((cA >> 4) & 3) << 2);
  int aoff = (jr >> 4) * 1024 + swA * 16 + ((koff & 4) << 1);
  int slotR = lane ^ (((lane >> 4) & 3) << 2);
  const float* xrow = X + (size_t)(jb + jr) * KIN + koff;

  // Stage w1/w2 into LDS (reads via lgkm, so they don't pollute vmcnt).
  {
    float2 a_ = *(const float2*)(w1 + t * 2);
    float2 b_ = *(const float2*)(w2 + t * 2);
    *(float2*)(wlds + t * 8) = a_;
    *(float2*)(wlds + 2048 + t * 8) = b_;
  }
  __syncthreads();

  float4 st0, st1, st2, st3;
  float d1 = 0.f, d2 = 0.f;
  f32x4 acc[2][4];
#pragma unroll
  for (int a = 0; a < 2; ++a)
#pragma unroll
    for (int b = 0; b < 4; ++b) acc[a][b] = (f32x4){0.f, 0.f, 0.f, 0.f};

#define K2_GLB(KT, BUFW)                                                      \
  do {                                                                        \
    const char* gs_ = WTbf + ((size_t)(KT) << 14) + (wv << 12) + lane * 16;   \
    char* ld_ = (BUFW) + 2048 + (wv << 12);                                   \
    GLDS(gs_, ld_);                                                           \
    GLDS(gs_ + 1024, ld_ + 1024);                                             \
    GLDS(gs_ + 2048, ld_ + 2048);                                             \
    GLDS(gs_ + 3072, ld_ + 3072);                                             \
  } while (0)

#define K2_LDX(KT, ST) (ST) = *(const float4*)(xrow + (KT) * 32)

#define K2_AGEN(ST, BUFW, SNUM)                                               \
  do {                                                                        \
    uint2 a_;                                                                 \
    a_.x = f2bf((ST).x) | (f2bf((ST).y) << 16);                               \
    a_.y = f2bf((ST).z) | (f2bf((ST).w) << 16);                               \
    *(uint2*)((BUFW) + aoff) = a_;                                            \
    float4 wa_ = *(const float4*)(wlds + ((SNUM)*32 + koff) * 4);             \
    float4 wb_ = *(const float4*)(wlds + 2048 + ((SNUM)*32 + koff) * 4);      \
    d1 += (ST).x * wa_.x + (ST).y * wa_.y + (ST).z * wa_.z + (ST).w * wa_.w;  \
    d2 += (ST).x * wb_.x + (ST).y * wb_.y + (ST).z * wb_.z + (ST).w * wb_.w;  \
  } while (0)

#define K2_ITER(S, BUFR, BUFW, STC, STF)                                      \
  do {                                                                        \
    int s_ = (S);                                                             \
    if (s_ + 1 < 16) K2_GLB(s_ + 1, BUFW);                                    \
    K2_LDX((s_ + 3 < 16) ? s_ + 3 : 15, STF);                                 \
    if (s_ + 1 < 16) K2_AGEN(STC, BUFW, s_ + 1);                              \
    bf16x8 a0 = *(const bf16x8*)((BUFR) + slotR * 16);                        \
    bf16x8 a1 = *(const bf16x8*)((BUFR) + 1024 + slotR * 16);                 \
    bf16x8 b0 = *(const bf16x8*)((BUFR) + 2048 + (wv * 4 + 0) * 1024 + lane * 16); \
    bf16x8 b1 = *(const bf16x8*)((BUFR) + 2048 + (wv * 4 + 1) * 1024 + lane * 16); \
    bf16x8 b2 = *(const bf16x8*)((BUFR) + 2048 + (wv * 4 + 2) * 1024 + lane * 16); \
    bf16x8 b3 = *(const bf16x8*)((BUFR) + 2048 + (wv * 4 + 3) * 1024 + lane * 16); \
    acc[0][0] = __builtin_amdgcn_mfma_f32_16x16x32_bf16(a0, b0, acc[0][0], 0, 0, 0); \
    acc[0][1] = __builtin_amdgcn_mfma_f32_16x16x32_bf16(a0, b1, acc[0][1], 0, 0, 0); \
    acc[0][2] = __builtin_amdgcn_mfma_f32_16x16x32_bf16(a0, b2, acc[0][2], 0, 0, 0); \
    acc[0][3] = __builtin_amdgcn_mfma_f32_16x16x32_bf16(a0, b3, acc[0][3], 0, 0, 0); \
    acc[1][0] = __builtin_amdgcn_mfma_f32_16x16x32_bf16(a1, b0, acc[1][0], 0, 0, 0); \
    acc[1][1] = __builtin_amdgcn_mfma_f32_16x16x32_bf16(a1, b1, acc[1][1], 0, 0, 0); \
    acc[1][2] = __builtin_amdgcn_mfma_f32_16x16x32_bf16(a1, b2, acc[1][2], 0, 0, 0); \
    acc[1][3] = __builtin_amdgcn_mfma_f32_16x16x32_bf16(a1, b3, acc[1][3], 0, 0, 0); \
    __builtin_amdgcn_sched_barrier(0);                                        \
    asm volatile("s_waitcnt vmcnt(1)");                                       \
    asm volatile("s_waitcnt lgkmcnt(0)");                                     \
    __builtin_amdgcn_s_barrier();                                             \
    __builtin_amdgcn_sched_barrier(0);                                        \
  } while (0)

  // Prologue
  K2_GLB(0, buf0);
  K2_LDX(0, st0);
  K2_LDX(1, st1);
  K2_LDX(2, st2);
  K2_AGEN(st0, buf0, 0);
  __builtin_amdgcn_sched_barrier(0);
  asm volatile("s_waitcnt vmcnt(2)");
  asm volatile("s_waitcnt lgkmcnt(0)");
  __builtin_amdgcn_s_barrier();
  __builtin_amdgcn_sched_barrier(0);

  for (int s4 = 0; s4 < 16; s4 += 4) {
    K2_ITER(s4 + 0, buf0, buf1, st1, st3);
    K2_ITER(s4 + 1, buf1, buf0, st2, st0);
    K2_ITER(s4 + 2, buf0, buf1, st3, st1);
    K2_ITER(s4 + 3, buf1, buf0, st0, st2);
  }
#undef K2_ITER
#undef K2_AGEN
#undef K2_LDX
#undef K2_GLB

  // Epilogue A: fragment image for this 32-j tile into buf0 B-area, copy out.
  int q = lane >> 4;
#pragma unroll
  for (int mi = 0; mi < 2; ++mi)
#pragma unroll
    for (int nn = 0; nn < 4; ++nn) {
      int u2 = wv * 4 + nn;
      int cell = (lane & 15) | ((((mi * 2) + (q >> 1)) & 3) << 4);
      uint2 v;
      v.x = f2bf(acc[mi][nn].x) | (f2bf(acc[mi][nn].y) << 16);
      v.y = f2bf(acc[mi][nn].z) | (f2bf(acc[mi][nn].w) << 16);
      *(uint2*)(buf0 + 2048 + u2 * 1024 + cell * 16 + ((q & 1) << 3)) = v;
    }
  __syncthreads();
  char* wb = WhTf + (size_t)blockIdx.x * 16384;
#pragma unroll
  for (int q2 = 0; q2 < 4; ++q2) {
    uint4 v = *(const uint4*)(buf0 + 2048 + q2 * 4096 + t * 16);
    *(uint4*)(wb + q2 * 4096 + t * 16) = v;
  }

  // Epilogue B: reduce Wh1/Wh2 over the 8 lanes sharing row jr, write, max.
  d1 += __shfl_xor(d1, 1);
  d1 += __shfl_xor(d1, 2);
  d1 += __shfl_xor(d1, 4);
  d2 += __shfl_xor(d2, 1);
  d2 += __shfl_xor(d2, 2);
  d2 += __shfl_xor(d2, 4);
  if ((t & 7) == 0) {
    Wh1[jb + jr] = d1;
    Wh2[jb + jr] = d2;
  }
  float mx = d2;
#pragma unroll
  for (int off = 32; off >= 8; off >>= 1) mx = fmaxf(mx, __shfl_xor(mx, off));
  __shared__ float red[4];
  if (lane == 0) red[wv] = mx;
  __syncthreads();
  if (t == 0) {
    float bm = fmaxf(fmaxf(red[0], red[1]), fmaxf(red[2], red[3]));
    atomicMax(maxkey, fkey(bm));
  }
}

// ---------------- k3: fused attention weights + PV matmul ----------------
__device__ __forceinline__ uint2 hv4(int4 aq, float4 wq, float wh1, float m,
                                     float enm, float& z) {
  float s0 = wh1 + wq.x, s1 = wh1 + wq.y, s2 = wh1 + wq.z, s3 = wh1 + wq.w;
  s0 = s0 > 0.f ? s0 : 0.2f * s0;
  s1 = s1 > 0.f ? s1 : 0.2f * s1;
  s2 = s2 > 0.f ? s2 : 0.2f * s2;
  s3 = s3 > 0.f ? s3 : 0.2f * s3;
  float w0 = aq.x > 0 ? __expf(s0 - m) : enm;
  float w1 = aq.y > 0 ? __expf(s1 - m) : enm;
  float w2 = aq.z > 0 ? __expf(s2 - m) : enm;
  float w3 = aq.w > 0 ? __expf(s3 - m) : enm;
  unsigned h0 = f2bf(w0), h1 = f2bf(w1), h2 = f2bf(w2), h3 = f2bf(w3);
  z += bf2f(h0) + bf2f(h1) + bf2f(h2) + bf2f(h3);
  uint2 r;
  r.x = h0 | (h1 << 16);
  r.y = h2 | (h3 << 16);
  return r;
}
__device__ __forceinline__ uint4 hv8(int4 a0, int4 a1, float4 w0, float4 w1,
                                     float wh1, float m, float enm, float& z) {
  uint2 r0 = hv4(a0, w0, wh1, m, enm, z);
  uint2 r1 = hv4(a1, w1, wh1, m, enm, z);
  return (uint4){r0.x, r0.y, r1.x, r1.y};
}

__global__ __launch_bounds__(1024, 4) void k3_attn(
    const int* __restrict__ adj, const char* __restrict__ WhTf,
    const float* __restrict__ Wh1, const float* __restrict__ Wh2,
    const unsigned* __restrict__ maxptr, float* __restrict__ PVp,
    float* __restrict__ Zp) {
  // [A dbuf 2 x 16KB][wh2 chunk 8KB] = 40960 B
  __shared__ char smem[40960];
  char* abuf0 = smem;
  char* abuf1 = smem + 16384;
  char* wlds = smem + 32768;
  int t = threadIdx.x, wv = t >> 6, lane = t & 63;
  int kc = blockIdx.x & 3;
  int ib = blockIdx.x >> 2;  // 0..63
  int ibase = ib * IROWS;
  int jbch = kc * JCHUNK;
  int r0 = t >> 3;           // row in tile 0..127
  int j8 = (t & 7) * 8;      // j offset 0..56
  int iglob = ibase + r0;
  float maxwh2 = fkey_dec(*maxptr);
  float wh1 = Wh1[iglob];
  float m = fmaxf(0.f, wh1 + maxwh2);
  float enm = __expf(-m);
  // A-image: unit = (r0>>4)*2 + ks (ks = j8>>5); cell = (r0&15)|(slot<<4);
  // thread writes one full 16B cell (its 8 j's).
  int unitA = (r0 >> 4) * 2 + (j8 >> 5);
  int cA = (r0 & 15) | (((j8 & 31) >> 3) << 4);
  int swA = cA ^ (((cA >> 4) & 3) << 2);
  int aoff = unitA * 1024 + swA * 16;
  int slotR = lane ^ (((lane >> 4) & 3) << 2);
  const int* adjrow = adj + ((size_t)iglob << 13) + jbch + j8;
  // Wave wv owns B unit wv (f = wv*16 + lane&15).
  const char* bbase = WhTf + ((size_t)(kc * 64) << 14) + (size_t)wv * 1024 +
                      (size_t)lane * 16;
  const char* wl = wlds + j8 * 4;

  // Stage this chunk's Wh2 (2048 floats = 8KB) into LDS once.
  *(float2*)(wlds + t * 8) = *(const float2*)(Wh2 + jbch + t * 2);
  __syncthreads();

  bf16x8 bA0, bA1, bB0, bB1;
  int4 st0_a, st0_b, st1_a, st1_b;
  f32x4 acc[8];
#pragma unroll
  for (int a = 0; a < 8; ++a) acc[a] = (f32x4){0.f, 0.f, 0.f, 0.f};
  float zacc = 0.f;

#define K3_LDB(S, B0, B1)                                                     \
  do {                                                                        \
    int sc_ = (S) < NSTEP ? (S) : NSTEP - 1;                                  \
    const char* bp_ = bbase + (size_t)(2 * sc_) * 16384;                      \
    B0 = *(const bf16x8*)(bp_);                                               \
    B1 = *(const bf16x8*)(bp_ + 16384);                                       \
  } while (0)

#define K3_LDA(S, ST)                                                         \
  do {                                                                        \
    int sc_ = (S) < NSTEP ? (S) : NSTEP - 1;                                  \
    ST##_a = *(const int4*)(adjrow + sc_ * BKJ);                              \
    ST##_b = *(const int4*)(adjrow + sc_ * BKJ + 4);                          \
  } while (0)

  // Iter S: B(S+1)->BF; hv consumes STC (= adj(S+1)), writes A(S+1) to AW;
  // refill STC <- adj(S+3); MFMA consumes A(S) from AR and B(S) from BC.
#define K3_ITER(S, AR, AW, BC0, BC1, BF0, BF1, STC, DO_HV)                    \
  do {                                                                        \
    int s_ = (S);                                                             \
    K3_LDB(s_ + 1, BF0, BF1);                                                 \
    if (DO_HV) {                                                              \
      float4 wq0_ = *(const float4*)(wl + (s_ + 1) * 256);                    \
      float4 wq1_ = *(const float4*)(wl + (s_ + 1) * 256 + 16);               \
      uint4 a_ = hv8(STC##_a, STC##_b, wq0_, wq1_, wh1, m, enm, zacc);        \
      *(uint4*)((AW) + aoff) = a_;                                            \
    }                                                                         \
    K3_LDA(s_ + 3, STC);                                                      \
    _Pragma("unroll")                                                         \
    for (int rf_ = 0; rf_ < 8; ++rf_) {                                       \
      bf16x8 ak0_ = *(const bf16x8*)((AR) + (rf_ * 2 + 0) * 1024 + slotR * 16); \
      bf16x8 ak1_ = *(const bf16x8*)((AR) + (rf_ * 2 + 1) * 1024 + slotR * 16); \
      acc[rf_] = __builtin_amdgcn_mfma_f32_16x16x32_bf16(ak0_, BC0, acc[rf_], 0, 0, 0); \
      acc[rf_] = __builtin_amdgcn_mfma_f32_16x16x32_bf16(ak1_, BC1, acc[rf_], 0, 0, 0); \
    }                                                                         \
    __builtin_amdgcn_sched_barrier(0);                                        \
    asm volatile("s_waitcnt lgkmcnt(0)" ::: "memory");                        \
    __builtin_amdgcn_s_barrier();                                             \
    __builtin_amdgcn_sched_barrier(0);                                        \
  } while (0)

  // Prologue: B(0)->bA; adj(0) immediate; adj(1)->st1, adj(2)->st0; A(0)->abuf0.
  K3_LDB(0, bA0, bA1);
  int4 adj0a = *(const int4*)(adjrow);
  int4 adj0b = *(const int4*)(adjrow + 4);
  K3_LDA(1, st1);
  K3_LDA(2, st0);
  {
    float4 wq0 = *(const float4*)(wl);
    float4 wq1 = *(const float4*)(wl + 16);
    uint4 a0 = hv8(adj0a, adj0b, wq0, wq1, wh1, m, enm, zacc);
    *(uint4*)(abuf0 + aoff) = a0;
  }
  __builtin_amdgcn_sched_barrier(0);
  asm volatile("s_waitcnt lgkmcnt(0)" ::: "memory");
  __builtin_amdgcn_s_barrier();
  __builtin_amdgcn_sched_barrier(0);

  for (int s2 = 0; s2 < NSTEP - 2; s2 += 2) {
    K3_ITER(s2 + 0, abuf0, abuf1, bA0, bA1, bB0, bB1, st1, 1);
    K3_ITER(s2 + 1, abuf1, abuf0, bB0, bB1, bA0, bA1, st0, 1);
  }
  K3_ITER(NSTEP - 2, abuf0, abuf1, bA0, bA1, bB0, bB1, st1, 1);
  K3_ITER(NSTEP - 1, abuf1, abuf0, bB0, bB1, bA0, bA1, st0, 0);
#undef K3_ITER
#undef K3_LDA
#undef K3_LDB

  // Z reduce over the 8 threads sharing row r0.
  zacc += __shfl_xor(zacc, 1);
  zacc += __shfl_xor(zacc, 2);
  zacc += __shfl_xor(zacc, 4);
  if ((t & 7) == 0) Zp[(size_t)kc * NR + iglob] = zacc;
#pragma unroll
  for (int rf = 0; rf < 8; ++rf) {
    int f = wv * 16 + (lane & 15);
    int row0 = ibase + rf * 16 + ((lane >> 4) << 2);
    size_t base = ((size_t)kc * NR + row0) * FOUT + f;
    PVp[base + 0 * FOUT] = acc[rf].x;
    PVp[base + 1 * FOUT] = acc[rf].y;
    PVp[base + 2 * FOUT] = acc[rf].z;
    PVp[base + 3 * FOUT] = acc[rf].w;
  }
}

// ---------------- k4: reduce partials, normalize, relu ----------------
__global__ __launch_bounds__(256) void k4_reduce(const float* __restrict__ PVp,
                                                 const float* __restrict__ Zp,
                                                 float* __restrict__ out) {
  int tid = blockIdx.x * 256 + threadIdx.x;  // 0..524287
  int i = tid >> 6;
  int f4 = (tid & 63) * 4;
  float z = Zp[i] + Zp[NR + i] + Zp[2 * NR + i] + Zp[3 * NR + i];
  float4 a = {0.f, 0.f, 0.f, 0.f};
#pragma unroll
  for (int c = 0; c < KSPLIT; ++c) {
    float4 p = *(const float4*)(PVp + ((size_t)c * NR + i) * FOUT + f4);
    a.x += p.x;
    a.y += p.y;
    a.z += p.z;
    a.w += p.w;
  }
  float inv = 1.f / z;
  float4 r;
  r.x = fmaxf(a.x * inv, 0.f);
  r.y = fmaxf(a.y * inv, 0.f);
  r.z = fmaxf(a.z * inv, 0.f);
  r.w = fmaxf(a.w * inv, 0.f);
  *(float4*)(out + (size_t)i * FOUT + f4) = r;
}

// ---------------- launch ----------------
extern "C" void kernel_launch(void* const* d_in, const int* in_sizes, int n_in,
                              void* d_out, int out_size, void* d_ws,
                              size_t ws_size, hipStream_t stream) {
  const float* X = (const float*)d_in[0];
  const float* W = (const float*)d_in[1];
  const float* W2 = (const float*)d_in[2];
  const int* adj = (const int*)d_in[3];
  float* out = (float*)d_out;
  char* ws = (char*)d_ws;

  const size_t WHT_OFF = 0;                               // 4 MB fragment image
  const size_t WTBF_OFF = (size_t)4 * 1024 * 1024;        // 256 KB
  const size_t W1_OFF = WTBF_OFF + 256 * 1024;
  const size_t W2V_OFF = W1_OFF + 2048;
  const size_t WH1_OFF = W2V_OFF + 2048;
  const size_t WH2_OFF = WH1_OFF + 32768;
  const size_t MXK_OFF = WH2_OFF + 32768;
  const size_t ZP_OFF = MXK_OFF + 256;                    // float[4][8192]
  const size_t PV_OFF = ZP_OFF + (size_t)KSPLIT * NR * 4; // float[4][8192][256]

  char* WhTf = ws + WHT_OFF;
  char* WTbf = ws + WTBF_OFF;
  float* w1 = (float*)(ws + W1_OFF);
  float* w2 = (float*)(ws + W2V_OFF);
  float* Wh1 = (float*)(ws + WH1_OFF);
  float* Wh2 = (float*)(ws + WH2_OFF);
  unsigned* maxkey = (unsigned*)(ws + MXK_OFF);
  float* Zp = (float*)(ws + ZP_OFF);
  float* PVp = (float*)(ws + PV_OFF);

  k0_prep<<<128, 256, 0, stream>>>(W, W2, w1, w2, WTbf, maxkey);
  k2_fused<<<256, 256, 0, stream>>>(X, WTbf, w1, w2, WhTf, Wh1, Wh2, maxkey);
  k3_attn<<<256, 1024, 0, stream>>>(adj, WhTf, Wh1, Wh2, maxkey, PVp, Zp);
  k4_reduce<<<2048, 256, 0, stream>>>(PVp, Zp, out);
}